// Round 1
// baseline (1284.058 us; speedup 1.0000x reference)
//
#include <hip/hip_runtime.h>

// MambaSkipConnection: B=4, C=192, H=W=64 (L=4096), DI=384, N=16, RK=12, DCONV=4
// Full fp32 implementation, 8 kernels.
// Workspace usage: 35,323,904 floats = 141.3 MB (requires ws_size >= 142 MB).

#define Bn 4
#define Cn 192
#define Hn 64
#define Wn 64
#define Ln 4096
#define DIn 384
#define Nst 16
#define RK 12
#define E2 768
#define EPSf 1e-5f

static __device__ __forceinline__ float sigmoidf_(float v) {
    return 1.f / (1.f + __expf(-v));
}
static __device__ __forceinline__ float softplusf_(float v) {
    return v > 20.f ? v : log1pf(__expf(v));
}

// ---------------------------------------------------------------- K1: LayerNorm
// x (B,C,L) -> tn (B*L, C) tokens, normalized over C.
__global__ __launch_bounds__(256) void k_ln(const float* __restrict__ x,
                                            const float* __restrict__ lnw,
                                            const float* __restrict__ lnb,
                                            float* __restrict__ tn) {
    __shared__ float tile[Cn][65];
    __shared__ float red[2][4][64];
    __shared__ float mean_s[64], rstd_s[64];
    int b = blockIdx.x >> 6;
    int l0 = (blockIdx.x & 63) << 6;
    int tid = threadIdx.x;
    for (int idx = tid; idx < Cn * 64; idx += 256) {
        int c = idx >> 6, ll = idx & 63;
        tile[c][ll] = x[((size_t)(b * Cn + c) << 12) + l0 + ll];
    }
    __syncthreads();
    int ll = tid & 63, grp = tid >> 6;  // 4 groups of 48 channels
    float s = 0.f, s2 = 0.f;
    for (int c = grp * 48; c < grp * 48 + 48; ++c) {
        float v = tile[c][ll];
        s += v; s2 += v * v;
    }
    red[0][grp][ll] = s; red[1][grp][ll] = s2;
    __syncthreads();
    if (tid < 64) {
        float m = red[0][0][tid] + red[0][1][tid] + red[0][2][tid] + red[0][3][tid];
        float q = red[1][0][tid] + red[1][1][tid] + red[1][2][tid] + red[1][3][tid];
        m *= (1.f / Cn);
        float var = q * (1.f / Cn) - m * m;
        mean_s[tid] = m;
        rstd_s[tid] = rsqrtf(var + EPSf);
    }
    __syncthreads();
    for (int idx = tid; idx < 64 * Cn; idx += 256) {
        int t = idx / Cn, c = idx - t * Cn;
        float v = (tile[c][t] - mean_s[t]) * rstd_s[t] * lnw[c] + lnb[c];
        tn[(size_t)(b * Ln + l0 + t) * Cn + c] = v;
    }
}

// ---------------------------------------------------------------- K2: tiled GEMM
// out[m,n] = sum_k A[m,k] * Wt[n,k];  A (M,K) rm, Wt (N,K) rm. BM=BN=64, BK=16.
template <int K>
__global__ __launch_bounds__(256) void k_gemm(const float* __restrict__ A,
                                              const float* __restrict__ Wt,
                                              float* __restrict__ out, int Nn) {
    __shared__ __align__(16) float As[16][68];
    __shared__ __align__(16) float Ws[16][68];
    int m0 = blockIdx.x << 6, n0 = blockIdx.y << 6;
    int tid = threadIdx.x;
    int lm = tid >> 2, lk = (tid & 3) << 2;
    int tm = (tid >> 4) << 2, tn4 = (tid & 15) << 2;
    float acc[4][4] = {};
    for (int k0 = 0; k0 < K; k0 += 16) {
        float4 a4 = *(const float4*)&A[(size_t)(m0 + lm) * K + k0 + lk];
        float4 w4 = *(const float4*)&Wt[(size_t)(n0 + lm) * K + k0 + lk];
        As[lk + 0][lm] = a4.x; As[lk + 1][lm] = a4.y; As[lk + 2][lm] = a4.z; As[lk + 3][lm] = a4.w;
        Ws[lk + 0][lm] = w4.x; Ws[lk + 1][lm] = w4.y; Ws[lk + 2][lm] = w4.z; Ws[lk + 3][lm] = w4.w;
        __syncthreads();
#pragma unroll
        for (int kk = 0; kk < 16; ++kk) {
            float4 av = *(const float4*)&As[kk][tm];
            float4 wv = *(const float4*)&Ws[kk][tn4];
            acc[0][0] = fmaf(av.x, wv.x, acc[0][0]);
            acc[0][1] = fmaf(av.x, wv.y, acc[0][1]);
            acc[0][2] = fmaf(av.x, wv.z, acc[0][2]);
            acc[0][3] = fmaf(av.x, wv.w, acc[0][3]);
            acc[1][0] = fmaf(av.y, wv.x, acc[1][0]);
            acc[1][1] = fmaf(av.y, wv.y, acc[1][1]);
            acc[1][2] = fmaf(av.y, wv.z, acc[1][2]);
            acc[1][3] = fmaf(av.y, wv.w, acc[1][3]);
            acc[2][0] = fmaf(av.z, wv.x, acc[2][0]);
            acc[2][1] = fmaf(av.z, wv.y, acc[2][1]);
            acc[2][2] = fmaf(av.z, wv.z, acc[2][2]);
            acc[2][3] = fmaf(av.z, wv.w, acc[2][3]);
            acc[3][0] = fmaf(av.w, wv.x, acc[3][0]);
            acc[3][1] = fmaf(av.w, wv.y, acc[3][1]);
            acc[3][2] = fmaf(av.w, wv.z, acc[3][2]);
            acc[3][3] = fmaf(av.w, wv.w, acc[3][3]);
        }
        __syncthreads();
    }
#pragma unroll
    for (int i = 0; i < 4; ++i) {
        float4 o;
        o.x = acc[i][0]; o.y = acc[i][1]; o.z = acc[i][2]; o.w = acc[i][3];
        *(float4*)&out[(size_t)(m0 + tm + i) * Nn + n0 + tn4] = o;
    }
}

// ---------------------------------------------------------------- K3: causal depthwise conv1d + SiLU
// xi = xz[:, :384]; xt[m,d] = silu(sum_k xi[m-3+k, d]*cw[d,k] + cb[d])
__global__ __launch_bounds__(256) void k_conv1d(const float* __restrict__ xz,
                                                const float* __restrict__ cw,
                                                const float* __restrict__ cb,
                                                float* __restrict__ xt) {
    int g = blockIdx.x * 256 + threadIdx.x;  // (B*L) * (DI/4)
    int m = g / 96, dq = g - m * 96;
    int d = dq << 2;
    int l = m & (Ln - 1);
    float w_[4][4];
    *(float4*)&w_[0][0] = *(const float4*)&cw[(d + 0) << 2];
    *(float4*)&w_[1][0] = *(const float4*)&cw[(d + 1) << 2];
    *(float4*)&w_[2][0] = *(const float4*)&cw[(d + 2) << 2];
    *(float4*)&w_[3][0] = *(const float4*)&cw[(d + 3) << 2];
    float4 bv = *(const float4*)&cb[d];
    float o_[4] = {bv.x, bv.y, bv.z, bv.w};
    const float* base = xz + (size_t)m * E2 + d;
#pragma unroll
    for (int j = 0; j < 4; ++j) {  // tap at token m-j uses weight index 3-j
        if (l >= j) {
            float4 in4 = *(const float4*)(base - (size_t)j * E2);
            o_[0] += in4.x * w_[0][3 - j];
            o_[1] += in4.y * w_[1][3 - j];
            o_[2] += in4.z * w_[2][3 - j];
            o_[3] += in4.w * w_[3][3 - j];
        }
    }
    float4 r;
    r.x = o_[0] * sigmoidf_(o_[0]);
    r.y = o_[1] * sigmoidf_(o_[1]);
    r.z = o_[2] * sigmoidf_(o_[2]);
    r.w = o_[3] * sigmoidf_(o_[3]);
    *(float4*)&xt[(size_t)m * DIn + d] = r;
}

// ---------------------------------------------------------------- K4: x_proj (N=44)
__global__ __launch_bounds__(256) void k_xproj(const float* __restrict__ xt,
                                               const float* __restrict__ xpw,
                                               float* __restrict__ dbl) {
    __shared__ float As[64][69];
    __shared__ float Ws_[64][45];  // [k][n]
    int m0 = blockIdx.x << 6, tid = threadIdx.x;
    int tok = tid & 63, nset = tid >> 6;  // 4 sets of 11 outputs
    float acc[11] = {};
    for (int k0 = 0; k0 < DIn; k0 += 64) {
        for (int idx = tid; idx < 64 * 64; idx += 256)
            As[idx >> 6][idx & 63] = xt[(size_t)(m0 + (idx >> 6)) * DIn + k0 + (idx & 63)];
        for (int idx = tid; idx < 44 * 64; idx += 256) {
            int n = idx >> 6, k = idx & 63;
            Ws_[k][n] = xpw[(size_t)n * DIn + k0 + k];
        }
        __syncthreads();
        for (int k = 0; k < 64; ++k) {
            float a = As[tok][k];
#pragma unroll
            for (int j = 0; j < 11; ++j)
                acc[j] = fmaf(a, Ws_[k][nset * 11 + j], acc[j]);
        }
        __syncthreads();
    }
#pragma unroll
    for (int j = 0; j < 11; ++j)
        dbl[(size_t)(m0 + tok) * 44 + nset * 11 + j] = acc[j];
}

// ---------------------------------------------------------------- K5: dt_proj + softplus
// delta[m,d] = softplus(sum_r dbl[m,r]*dtw[d,r] + dtb[d]);  delta layout (B*L, DI)
__global__ __launch_bounds__(256) void k_dtproj(const float* __restrict__ dbl,
                                                const float* __restrict__ dtw,
                                                const float* __restrict__ dtb,
                                                float* __restrict__ delta) {
    __shared__ float dts[64][13];
    __shared__ float wls[RK][DIn];  // transposed
    __shared__ float bls[DIn];
    int m0 = blockIdx.x << 6, tid = threadIdx.x;
    for (int idx = tid; idx < 64 * RK; idx += 256) {
        int t = idx / RK, r = idx - t * RK;
        dts[t][r] = dbl[(size_t)(m0 + t) * 44 + r];
    }
    for (int idx = tid; idx < DIn * RK; idx += 256) {
        int dd = idx / RK, r = idx - dd * RK;
        wls[r][dd] = dtw[idx];
    }
    for (int idx = tid; idx < DIn; idx += 256) bls[idx] = dtb[idx];
    __syncthreads();
    for (int i = 0; i < 96; ++i) {
        int idx = tid + (i << 8);
        int t = idx / DIn, dd = idx - t * DIn;
        float acc = bls[dd];
#pragma unroll
        for (int r = 0; r < RK; ++r) acc = fmaf(dts[t][r], wls[r][dd], acc);
        delta[(size_t)(m0 + t) * DIn + dd] = softplusf_(acc);
    }
}

// ---------------------------------------------------------------- K6: selective scan
// 16 lanes per (b,d) channel (lane = state n); h recurrence over L; y staged in LDS.
__global__ __launch_bounds__(256) void k_scan(const float* __restrict__ delta,
                                              const float* __restrict__ xt,
                                              const float* __restrict__ dbl,
                                              const float* __restrict__ alog,
                                              float* __restrict__ ys) {
    __shared__ float pbuf[32][16][17];
    int b = blockIdx.x / 24, dg = blockIdx.x % 24;
    int tid = threadIdx.x, ch = tid >> 4, n = tid & 15;
    int d = dg * 16 + ch;
    float Av = -__expf(alog[d * Nst + n]);
    float h = 0.f;
    const float* dp = delta + (size_t)b * Ln * DIn + d;
    const float* up = xt + (size_t)b * Ln * DIn + d;
    const float* bp = dbl + (size_t)b * Ln * 44 + 12 + n;
    const float* cp = dbl + (size_t)b * Ln * 44 + 28 + n;
    for (int t0 = 0; t0 < Ln; t0 += 32) {
        for (int tt = 0; tt < 32; tt += 4) {
            float de[4], uu[4], bb[4], cv[4];
#pragma unroll
            for (int j = 0; j < 4; ++j) {
                size_t t = t0 + tt + j;
                de[j] = dp[t * DIn];
                uu[j] = up[t * DIn];
                bb[j] = bp[t * 44];
                cv[j] = cp[t * 44];
            }
#pragma unroll
            for (int j = 0; j < 4; ++j) {
                float dA = __expf(de[j] * Av);
                h = fmaf(dA, h, de[j] * uu[j] * bb[j]);
                pbuf[tt + j][ch][n] = h * cv[j];
            }
        }
        __syncthreads();
#pragma unroll
        for (int r = 0; r < 2; ++r) {
            int idx = tid + (r << 8);
            int t = idx >> 4, c2 = idx & 15;
            float s = 0.f;
#pragma unroll
            for (int q = 0; q < 16; ++q) s += pbuf[t][c2][q];
            ys[(size_t)(b * Ln + t0 + t) * DIn + dg * 16 + c2] = s;
        }
        __syncthreads();
    }
}

// ---------------------------------------------------------------- K7: gate + out_proj + residual
// t2[m,c] = x[b,c,l] + sum_d ((ys+xt*D)*silu(z))[m,d] * Wo[c,d]
__global__ __launch_bounds__(256) void k_gate(const float* __restrict__ ys,
                                              const float* __restrict__ xt,
                                              const float* __restrict__ xz,
                                              const float* __restrict__ Dp,
                                              const float* __restrict__ Wo,
                                              const float* __restrict__ x,
                                              float* __restrict__ t2) {
    __shared__ __align__(16) float As[16][68];
    __shared__ __align__(16) float Ws[16][68];
    int m0 = blockIdx.x << 6, n0 = blockIdx.y << 6;
    int tid = threadIdx.x;
    int lm = tid >> 2, lk = (tid & 3) << 2;
    int tm = (tid >> 4) << 2, tn4 = (tid & 15) << 2;
    float acc[4][4] = {};
    for (int k0 = 0; k0 < DIn; k0 += 16) {
        size_t arow = (size_t)(m0 + lm) * DIn + k0 + lk;
        float4 y4 = *(const float4*)&ys[arow];
        float4 u4 = *(const float4*)&xt[arow];
        float4 z4 = *(const float4*)&xz[(size_t)(m0 + lm) * E2 + DIn + k0 + lk];
        float4 d4 = *(const float4*)&Dp[k0 + lk];
        As[lk + 0][lm] = (y4.x + u4.x * d4.x) * (z4.x * sigmoidf_(z4.x));
        As[lk + 1][lm] = (y4.y + u4.y * d4.y) * (z4.y * sigmoidf_(z4.y));
        As[lk + 2][lm] = (y4.z + u4.z * d4.z) * (z4.z * sigmoidf_(z4.z));
        As[lk + 3][lm] = (y4.w + u4.w * d4.w) * (z4.w * sigmoidf_(z4.w));
        float4 w4 = *(const float4*)&Wo[(size_t)(n0 + lm) * DIn + k0 + lk];
        Ws[lk + 0][lm] = w4.x; Ws[lk + 1][lm] = w4.y; Ws[lk + 2][lm] = w4.z; Ws[lk + 3][lm] = w4.w;
        __syncthreads();
#pragma unroll
        for (int kk = 0; kk < 16; ++kk) {
            float4 av = *(const float4*)&As[kk][tm];
            float4 wv = *(const float4*)&Ws[kk][tn4];
            acc[0][0] = fmaf(av.x, wv.x, acc[0][0]);
            acc[0][1] = fmaf(av.x, wv.y, acc[0][1]);
            acc[0][2] = fmaf(av.x, wv.z, acc[0][2]);
            acc[0][3] = fmaf(av.x, wv.w, acc[0][3]);
            acc[1][0] = fmaf(av.y, wv.x, acc[1][0]);
            acc[1][1] = fmaf(av.y, wv.y, acc[1][1]);
            acc[1][2] = fmaf(av.y, wv.z, acc[1][2]);
            acc[1][3] = fmaf(av.y, wv.w, acc[1][3]);
            acc[2][0] = fmaf(av.z, wv.x, acc[2][0]);
            acc[2][1] = fmaf(av.z, wv.y, acc[2][1]);
            acc[2][2] = fmaf(av.z, wv.z, acc[2][2]);
            acc[2][3] = fmaf(av.z, wv.w, acc[2][3]);
            acc[3][0] = fmaf(av.w, wv.x, acc[3][0]);
            acc[3][1] = fmaf(av.w, wv.y, acc[3][1]);
            acc[3][2] = fmaf(av.w, wv.z, acc[3][2]);
            acc[3][3] = fmaf(av.w, wv.w, acc[3][3]);
        }
        __syncthreads();
    }
#pragma unroll
    for (int i = 0; i < 4; ++i) {
        int mm = m0 + tm + i;
        int b = mm >> 12, l = mm & 4095;
        float4 o;
        o.x = acc[i][0] + x[((size_t)(b * Cn + n0 + tn4 + 0) << 12) + l];
        o.y = acc[i][1] + x[((size_t)(b * Cn + n0 + tn4 + 1) << 12) + l];
        o.z = acc[i][2] + x[((size_t)(b * Cn + n0 + tn4 + 2) << 12) + l];
        o.w = acc[i][3] + x[((size_t)(b * Cn + n0 + tn4 + 3) << 12) + l];
        *(float4*)&t2[(size_t)mm * Cn + n0 + tn4] = o;
    }
}

// ---------------------------------------------------------------- K8: conv3x3 + BN + ReLU
// t2 as NHWC (B, HW, C); out NCHW. Block: 16x16 spatial x 16 c_out; thread: 2x2 sp x 4 co.
__global__ __launch_bounds__(256) void k_conv3(const float* __restrict__ t2,
                                               const float* __restrict__ rfw,
                                               const float* __restrict__ rfb,
                                               const float* __restrict__ bnw,
                                               const float* __restrict__ bnb,
                                               const float* __restrict__ bnm,
                                               const float* __restrict__ bnv,
                                               float* __restrict__ out) {
    __shared__ __align__(16) float ins[324][20];   // 18x18 spatial x 16 ci (+pad)
    __shared__ __align__(16) float wls[16][9][16]; // co, tap, ci
    int h0 = (blockIdx.x >> 2) << 4, w0 = (blockIdx.x & 3) << 4;
    int c0 = blockIdx.y << 4, b = blockIdx.z;
    int tid = threadIdx.x;
    int coq = tid >> 6, sh = (tid & 63) >> 3, sw = tid & 7;
    float acc[4][4] = {};  // [co j][di*2+dj]
    for (int ci0 = 0; ci0 < Cn; ci0 += 16) {
        for (int idx = tid; idx < 324 * 16; idx += 256) {
            int sp = idx >> 4, ci = idx & 15;
            int hh = h0 - 1 + sp / 18, ww = w0 - 1 + sp % 18;
            float v = 0.f;
            if (hh >= 0 && hh < Hn && ww >= 0 && ww < Wn)
                v = t2[((size_t)(b << 12) + (hh << 6) + ww) * Cn + ci0 + ci];
            ins[sp][ci] = v;
        }
        for (int idx = tid; idx < 16 * 9 * 16; idx += 256) {
            int co = idx / 144, r = idx - co * 144;
            int tap = r >> 4, ci = r & 15;
            wls[co][tap][ci] = rfw[((size_t)(c0 + co) * Cn + ci0 + ci) * 9 + tap];
        }
        __syncthreads();
#pragma unroll
        for (int tap = 0; tap < 9; ++tap) {
            int dh = tap / 3, dw = tap % 3;
#pragma unroll
            for (int c4 = 0; c4 < 16; c4 += 4) {
                float4 wv0 = *(const float4*)&wls[coq * 4 + 0][tap][c4];
                float4 wv1 = *(const float4*)&wls[coq * 4 + 1][tap][c4];
                float4 wv2 = *(const float4*)&wls[coq * 4 + 2][tap][c4];
                float4 wv3 = *(const float4*)&wls[coq * 4 + 3][tap][c4];
#pragma unroll
                for (int di = 0; di < 2; ++di)
#pragma unroll
                    for (int dj = 0; dj < 2; ++dj) {
                        int sp = (sh * 2 + di + dh) * 18 + (sw * 2 + dj + dw);
                        float4 iv = *(const float4*)&ins[sp][c4];
                        int s = di * 2 + dj;
                        acc[0][s] += iv.x * wv0.x + iv.y * wv0.y + iv.z * wv0.z + iv.w * wv0.w;
                        acc[1][s] += iv.x * wv1.x + iv.y * wv1.y + iv.z * wv1.z + iv.w * wv1.w;
                        acc[2][s] += iv.x * wv2.x + iv.y * wv2.y + iv.z * wv2.z + iv.w * wv2.w;
                        acc[3][s] += iv.x * wv3.x + iv.y * wv3.y + iv.z * wv3.z + iv.w * wv3.w;
                    }
            }
        }
        __syncthreads();
    }
#pragma unroll
    for (int j = 0; j < 4; ++j) {
        int c = c0 + coq * 4 + j;
        float sc = bnw[c] * rsqrtf(bnv[c] + EPSf);
        float sf = (rfb[c] - bnm[c]) * sc + bnb[c];
#pragma unroll
        for (int di = 0; di < 2; ++di)
#pragma unroll
            for (int dj = 0; dj < 2; ++dj) {
                float v = acc[j][di * 2 + dj] * sc + sf;
                v = fmaxf(v, 0.f);
                out[((size_t)(b * Cn + c) << 12) + ((h0 + sh * 2 + di) << 6) + (w0 + sw * 2 + dj)] = v;
            }
    }
}

// ----------------------------------------------------------------
extern "C" void kernel_launch(void* const* d_in, const int* in_sizes, int n_in,
                              void* d_out, int out_size, void* d_ws, size_t ws_size,
                              hipStream_t stream) {
    const float* x    = (const float*)d_in[0];
    const float* lnw  = (const float*)d_in[1];
    const float* lnb  = (const float*)d_in[2];
    const float* inpw = (const float*)d_in[3];
    const float* cw   = (const float*)d_in[4];
    const float* cb   = (const float*)d_in[5];
    const float* xpw  = (const float*)d_in[6];
    const float* dtw  = (const float*)d_in[7];
    const float* dtb  = (const float*)d_in[8];
    const float* alog = (const float*)d_in[9];
    const float* Dp   = (const float*)d_in[10];
    const float* Wo   = (const float*)d_in[11];
    const float* rfw  = (const float*)d_in[12];
    const float* rfb  = (const float*)d_in[13];
    const float* bnw  = (const float*)d_in[14];
    const float* bnb  = (const float*)d_in[15];
    const float* bnm  = (const float*)d_in[16];
    const float* bnv  = (const float*)d_in[17];

    float* ws    = (float*)d_ws;
    float* tn    = ws;              // 3,145,728 floats (reused as t2 after in_proj)
    float* xz    = ws + 3145728;    // 12,582,912
    float* xt    = ws + 15728640;   // 6,291,456
    float* dbl   = ws + 22020096;   // 720,896
    float* delta = ws + 22740992;   // 6,291,456
    float* ysb   = ws + 29032448;   // 6,291,456  (end: 35,323,904 floats)
    float* t2    = tn;              // reuse: tn dead after in_proj GEMM

    k_ln<<<Bn * (Ln / 64), 256, 0, stream>>>(x, lnw, lnb, tn);
    k_gemm<Cn><<<dim3((Bn * Ln) / 64, E2 / 64), 256, 0, stream>>>(tn, inpw, xz, E2);
    k_conv1d<<<(Bn * Ln * (DIn / 4)) / 256, 256, 0, stream>>>(xz, cw, cb, xt);
    k_xproj<<<(Bn * Ln) / 64, 256, 0, stream>>>(xt, xpw, dbl);
    k_dtproj<<<(Bn * Ln) / 64, 256, 0, stream>>>(dbl, dtw, dtb, delta);
    k_scan<<<Bn * (DIn / 16), 256, 0, stream>>>(delta, xt, dbl, alog, ysb);
    k_gate<<<dim3((Bn * Ln) / 64, Cn / 64), 256, 0, stream>>>(ysb, xt, xz, Dp, Wo, x, t2);
    k_conv3<<<dim3(16, Cn / 16, Bn), 256, 0, stream>>>(t2, rfw, rfb, bnw, bnb, bnm, bnv,
                                                       (float*)d_out);
}

// Round 2
// 782.563 us; speedup vs baseline: 1.6408x; 1.6408x over previous
//
#include <hip/hip_runtime.h>

// MambaSkipConnection: B=4, C=192, H=W=64 (L=4096), DI=384, N=16, RK=12, DCONV=4
// Round 2: conv3x3 -> bf16 MFMA implicit GEMM. Rest unchanged (fp32).
// Workspace usage: 35,323,904 floats = 141.3 MB (wcv aliases dead delta region).

#define Bn 4
#define Cn 192
#define Hn 64
#define Wn 64
#define Ln 4096
#define DIn 384
#define Nst 16
#define RK 12
#define E2 768
#define EPSf 1e-5f

typedef __bf16 bf16x8 __attribute__((ext_vector_type(8)));
typedef float f32x4 __attribute__((ext_vector_type(4)));
typedef unsigned short u16;
typedef unsigned int u32;

static __device__ __forceinline__ float sigmoidf_(float v) {
    return 1.f / (1.f + __expf(-v));
}
static __device__ __forceinline__ float softplusf_(float v) {
    return v > 20.f ? v : log1pf(__expf(v));
}
static __device__ __forceinline__ u16 f2bf(float f) {
    u32 u = __float_as_uint(f);
    u32 r = (u + 0x7FFFu + ((u >> 16) & 1u)) >> 16;
    return (u16)r;
}

// ---------------------------------------------------------------- K1: LayerNorm
__global__ __launch_bounds__(256) void k_ln(const float* __restrict__ x,
                                            const float* __restrict__ lnw,
                                            const float* __restrict__ lnb,
                                            float* __restrict__ tn) {
    __shared__ float tile[Cn][65];
    __shared__ float red[2][4][64];
    __shared__ float mean_s[64], rstd_s[64];
    int b = blockIdx.x >> 6;
    int l0 = (blockIdx.x & 63) << 6;
    int tid = threadIdx.x;
    for (int idx = tid; idx < Cn * 64; idx += 256) {
        int c = idx >> 6, ll = idx & 63;
        tile[c][ll] = x[((size_t)(b * Cn + c) << 12) + l0 + ll];
    }
    __syncthreads();
    int ll = tid & 63, grp = tid >> 6;
    float s = 0.f, s2 = 0.f;
    for (int c = grp * 48; c < grp * 48 + 48; ++c) {
        float v = tile[c][ll];
        s += v; s2 += v * v;
    }
    red[0][grp][ll] = s; red[1][grp][ll] = s2;
    __syncthreads();
    if (tid < 64) {
        float m = red[0][0][tid] + red[0][1][tid] + red[0][2][tid] + red[0][3][tid];
        float q = red[1][0][tid] + red[1][1][tid] + red[1][2][tid] + red[1][3][tid];
        m *= (1.f / Cn);
        float var = q * (1.f / Cn) - m * m;
        mean_s[tid] = m;
        rstd_s[tid] = rsqrtf(var + EPSf);
    }
    __syncthreads();
    for (int idx = tid; idx < 64 * Cn; idx += 256) {
        int t = idx / Cn, c = idx - t * Cn;
        float v = (tile[c][t] - mean_s[t]) * rstd_s[t] * lnw[c] + lnb[c];
        tn[(size_t)(b * Ln + l0 + t) * Cn + c] = v;
    }
}

// ---------------------------------------------------------------- K2: tiled GEMM (fp32)
template <int K>
__global__ __launch_bounds__(256) void k_gemm(const float* __restrict__ A,
                                              const float* __restrict__ Wt,
                                              float* __restrict__ out, int Nn) {
    __shared__ __align__(16) float As[16][68];
    __shared__ __align__(16) float Ws[16][68];
    int m0 = blockIdx.x << 6, n0 = blockIdx.y << 6;
    int tid = threadIdx.x;
    int lm = tid >> 2, lk = (tid & 3) << 2;
    int tm = (tid >> 4) << 2, tn4 = (tid & 15) << 2;
    float acc[4][4] = {};
    for (int k0 = 0; k0 < K; k0 += 16) {
        float4 a4 = *(const float4*)&A[(size_t)(m0 + lm) * K + k0 + lk];
        float4 w4 = *(const float4*)&Wt[(size_t)(n0 + lm) * K + k0 + lk];
        As[lk + 0][lm] = a4.x; As[lk + 1][lm] = a4.y; As[lk + 2][lm] = a4.z; As[lk + 3][lm] = a4.w;
        Ws[lk + 0][lm] = w4.x; Ws[lk + 1][lm] = w4.y; Ws[lk + 2][lm] = w4.z; Ws[lk + 3][lm] = w4.w;
        __syncthreads();
#pragma unroll
        for (int kk = 0; kk < 16; ++kk) {
            float4 av = *(const float4*)&As[kk][tm];
            float4 wv = *(const float4*)&Ws[kk][tn4];
            acc[0][0] = fmaf(av.x, wv.x, acc[0][0]);
            acc[0][1] = fmaf(av.x, wv.y, acc[0][1]);
            acc[0][2] = fmaf(av.x, wv.z, acc[0][2]);
            acc[0][3] = fmaf(av.x, wv.w, acc[0][3]);
            acc[1][0] = fmaf(av.y, wv.x, acc[1][0]);
            acc[1][1] = fmaf(av.y, wv.y, acc[1][1]);
            acc[1][2] = fmaf(av.y, wv.z, acc[1][2]);
            acc[1][3] = fmaf(av.y, wv.w, acc[1][3]);
            acc[2][0] = fmaf(av.z, wv.x, acc[2][0]);
            acc[2][1] = fmaf(av.z, wv.y, acc[2][1]);
            acc[2][2] = fmaf(av.z, wv.z, acc[2][2]);
            acc[2][3] = fmaf(av.z, wv.w, acc[2][3]);
            acc[3][0] = fmaf(av.w, wv.x, acc[3][0]);
            acc[3][1] = fmaf(av.w, wv.y, acc[3][1]);
            acc[3][2] = fmaf(av.w, wv.z, acc[3][2]);
            acc[3][3] = fmaf(av.w, wv.w, acc[3][3]);
        }
        __syncthreads();
    }
#pragma unroll
    for (int i = 0; i < 4; ++i) {
        float4 o;
        o.x = acc[i][0]; o.y = acc[i][1]; o.z = acc[i][2]; o.w = acc[i][3];
        *(float4*)&out[(size_t)(m0 + tm + i) * Nn + n0 + tn4] = o;
    }
}

// ---------------------------------------------------------------- K3: causal depthwise conv1d + SiLU
__global__ __launch_bounds__(256) void k_conv1d(const float* __restrict__ xz,
                                                const float* __restrict__ cw,
                                                const float* __restrict__ cb,
                                                float* __restrict__ xt) {
    int g = blockIdx.x * 256 + threadIdx.x;
    int m = g / 96, dq = g - m * 96;
    int d = dq << 2;
    int l = m & (Ln - 1);
    float w_[4][4];
    *(float4*)&w_[0][0] = *(const float4*)&cw[(d + 0) << 2];
    *(float4*)&w_[1][0] = *(const float4*)&cw[(d + 1) << 2];
    *(float4*)&w_[2][0] = *(const float4*)&cw[(d + 2) << 2];
    *(float4*)&w_[3][0] = *(const float4*)&cw[(d + 3) << 2];
    float4 bv = *(const float4*)&cb[d];
    float o_[4] = {bv.x, bv.y, bv.z, bv.w};
    const float* base = xz + (size_t)m * E2 + d;
#pragma unroll
    for (int j = 0; j < 4; ++j) {
        if (l >= j) {
            float4 in4 = *(const float4*)(base - (size_t)j * E2);
            o_[0] += in4.x * w_[0][3 - j];
            o_[1] += in4.y * w_[1][3 - j];
            o_[2] += in4.z * w_[2][3 - j];
            o_[3] += in4.w * w_[3][3 - j];
        }
    }
    float4 r;
    r.x = o_[0] * sigmoidf_(o_[0]);
    r.y = o_[1] * sigmoidf_(o_[1]);
    r.z = o_[2] * sigmoidf_(o_[2]);
    r.w = o_[3] * sigmoidf_(o_[3]);
    *(float4*)&xt[(size_t)m * DIn + d] = r;
}

// ---------------------------------------------------------------- K4: x_proj (N=44)
__global__ __launch_bounds__(256) void k_xproj(const float* __restrict__ xt,
                                               const float* __restrict__ xpw,
                                               float* __restrict__ dbl) {
    __shared__ float As[64][69];
    __shared__ float Ws_[64][45];
    int m0 = blockIdx.x << 6, tid = threadIdx.x;
    int tok = tid & 63, nset = tid >> 6;
    float acc[11] = {};
    for (int k0 = 0; k0 < DIn; k0 += 64) {
        for (int idx = tid; idx < 64 * 64; idx += 256)
            As[idx >> 6][idx & 63] = xt[(size_t)(m0 + (idx >> 6)) * DIn + k0 + (idx & 63)];
        for (int idx = tid; idx < 44 * 64; idx += 256) {
            int n = idx >> 6, k = idx & 63;
            Ws_[k][n] = xpw[(size_t)n * DIn + k0 + k];
        }
        __syncthreads();
        for (int k = 0; k < 64; ++k) {
            float a = As[tok][k];
#pragma unroll
            for (int j = 0; j < 11; ++j)
                acc[j] = fmaf(a, Ws_[k][nset * 11 + j], acc[j]);
        }
        __syncthreads();
    }
#pragma unroll
    for (int j = 0; j < 11; ++j)
        dbl[(size_t)(m0 + tok) * 44 + nset * 11 + j] = acc[j];
}

// ---------------------------------------------------------------- K5: dt_proj + softplus
__global__ __launch_bounds__(256) void k_dtproj(const float* __restrict__ dbl,
                                                const float* __restrict__ dtw,
                                                const float* __restrict__ dtb,
                                                float* __restrict__ delta) {
    __shared__ float dts[64][13];
    __shared__ float wls[RK][DIn];
    __shared__ float bls[DIn];
    int m0 = blockIdx.x << 6, tid = threadIdx.x;
    for (int idx = tid; idx < 64 * RK; idx += 256) {
        int t = idx / RK, r = idx - t * RK;
        dts[t][r] = dbl[(size_t)(m0 + t) * 44 + r];
    }
    for (int idx = tid; idx < DIn * RK; idx += 256) {
        int dd = idx / RK, r = idx - dd * RK;
        wls[r][dd] = dtw[idx];
    }
    for (int idx = tid; idx < DIn; idx += 256) bls[idx] = dtb[idx];
    __syncthreads();
    for (int i = 0; i < 96; ++i) {
        int idx = tid + (i << 8);
        int t = idx / DIn, dd = idx - t * DIn;
        float acc = bls[dd];
#pragma unroll
        for (int r = 0; r < RK; ++r) acc = fmaf(dts[t][r], wls[r][dd], acc);
        delta[(size_t)(m0 + t) * DIn + dd] = softplusf_(acc);
    }
}

// ---------------------------------------------------------------- K6: selective scan
__global__ __launch_bounds__(256) void k_scan(const float* __restrict__ delta,
                                              const float* __restrict__ xt,
                                              const float* __restrict__ dbl,
                                              const float* __restrict__ alog,
                                              float* __restrict__ ys) {
    __shared__ float pbuf[32][16][17];
    int b = blockIdx.x / 24, dg = blockIdx.x % 24;
    int tid = threadIdx.x, ch = tid >> 4, n = tid & 15;
    int d = dg * 16 + ch;
    float Av = -__expf(alog[d * Nst + n]);
    float h = 0.f;
    const float* dp = delta + (size_t)b * Ln * DIn + d;
    const float* up = xt + (size_t)b * Ln * DIn + d;
    const float* bp = dbl + (size_t)b * Ln * 44 + 12 + n;
    const float* cp = dbl + (size_t)b * Ln * 44 + 28 + n;
    for (int t0 = 0; t0 < Ln; t0 += 32) {
        for (int tt = 0; tt < 32; tt += 4) {
            float de[4], uu[4], bb[4], cv[4];
#pragma unroll
            for (int j = 0; j < 4; ++j) {
                size_t t = t0 + tt + j;
                de[j] = dp[t * DIn];
                uu[j] = up[t * DIn];
                bb[j] = bp[t * 44];
                cv[j] = cp[t * 44];
            }
#pragma unroll
            for (int j = 0; j < 4; ++j) {
                float dA = __expf(de[j] * Av);
                h = fmaf(dA, h, de[j] * uu[j] * bb[j]);
                pbuf[tt + j][ch][n] = h * cv[j];
            }
        }
        __syncthreads();
#pragma unroll
        for (int r = 0; r < 2; ++r) {
            int idx = tid + (r << 8);
            int t = idx >> 4, c2 = idx & 15;
            float s = 0.f;
#pragma unroll
            for (int q = 0; q < 16; ++q) s += pbuf[t][c2][q];
            ys[(size_t)(b * Ln + t0 + t) * DIn + dg * 16 + c2] = s;
        }
        __syncthreads();
    }
}

// ---------------------------------------------------------------- K7: gate + out_proj + residual
// writes t2 as bf16 NHWC (consumed by MFMA conv3x3)
__global__ __launch_bounds__(256) void k_gate(const float* __restrict__ ys,
                                              const float* __restrict__ xt,
                                              const float* __restrict__ xz,
                                              const float* __restrict__ Dp,
                                              const float* __restrict__ Wo,
                                              const float* __restrict__ x,
                                              u16* __restrict__ t2bf) {
    __shared__ __align__(16) float As[16][68];
    __shared__ __align__(16) float Ws[16][68];
    int m0 = blockIdx.x << 6, n0 = blockIdx.y << 6;
    int tid = threadIdx.x;
    int lm = tid >> 2, lk = (tid & 3) << 2;
    int tm = (tid >> 4) << 2, tn4 = (tid & 15) << 2;
    float acc[4][4] = {};
    for (int k0 = 0; k0 < DIn; k0 += 16) {
        size_t arow = (size_t)(m0 + lm) * DIn + k0 + lk;
        float4 y4 = *(const float4*)&ys[arow];
        float4 u4 = *(const float4*)&xt[arow];
        float4 z4 = *(const float4*)&xz[(size_t)(m0 + lm) * E2 + DIn + k0 + lk];
        float4 d4 = *(const float4*)&Dp[k0 + lk];
        As[lk + 0][lm] = (y4.x + u4.x * d4.x) * (z4.x * sigmoidf_(z4.x));
        As[lk + 1][lm] = (y4.y + u4.y * d4.y) * (z4.y * sigmoidf_(z4.y));
        As[lk + 2][lm] = (y4.z + u4.z * d4.z) * (z4.z * sigmoidf_(z4.z));
        As[lk + 3][lm] = (y4.w + u4.w * d4.w) * (z4.w * sigmoidf_(z4.w));
        float4 w4 = *(const float4*)&Wo[(size_t)(n0 + lm) * DIn + k0 + lk];
        Ws[lk + 0][lm] = w4.x; Ws[lk + 1][lm] = w4.y; Ws[lk + 2][lm] = w4.z; Ws[lk + 3][lm] = w4.w;
        __syncthreads();
#pragma unroll
        for (int kk = 0; kk < 16; ++kk) {
            float4 av = *(const float4*)&As[kk][tm];
            float4 wv = *(const float4*)&Ws[kk][tn4];
            acc[0][0] = fmaf(av.x, wv.x, acc[0][0]);
            acc[0][1] = fmaf(av.x, wv.y, acc[0][1]);
            acc[0][2] = fmaf(av.x, wv.z, acc[0][2]);
            acc[0][3] = fmaf(av.x, wv.w, acc[0][3]);
            acc[1][0] = fmaf(av.y, wv.x, acc[1][0]);
            acc[1][1] = fmaf(av.y, wv.y, acc[1][1]);
            acc[1][2] = fmaf(av.y, wv.z, acc[1][2]);
            acc[1][3] = fmaf(av.y, wv.w, acc[1][3]);
            acc[2][0] = fmaf(av.z, wv.x, acc[2][0]);
            acc[2][1] = fmaf(av.z, wv.y, acc[2][1]);
            acc[2][2] = fmaf(av.z, wv.z, acc[2][2]);
            acc[2][3] = fmaf(av.z, wv.w, acc[2][3]);
            acc[3][0] = fmaf(av.w, wv.x, acc[3][0]);
            acc[3][1] = fmaf(av.w, wv.y, acc[3][1]);
            acc[3][2] = fmaf(av.w, wv.z, acc[3][2]);
            acc[3][3] = fmaf(av.w, wv.w, acc[3][3]);
        }
        __syncthreads();
    }
#pragma unroll
    for (int i = 0; i < 4; ++i) {
        int mm = m0 + tm + i;
        int b = mm >> 12, l = mm & 4095;
        float4 o;
        o.x = acc[i][0] + x[((size_t)(b * Cn + n0 + tn4 + 0) << 12) + l];
        o.y = acc[i][1] + x[((size_t)(b * Cn + n0 + tn4 + 1) << 12) + l];
        o.z = acc[i][2] + x[((size_t)(b * Cn + n0 + tn4 + 2) << 12) + l];
        o.w = acc[i][3] + x[((size_t)(b * Cn + n0 + tn4 + 3) << 12) + l];
        ushort4 ob;
        ob.x = f2bf(o.x); ob.y = f2bf(o.y); ob.z = f2bf(o.z); ob.w = f2bf(o.w);
        *(ushort4*)&t2bf[(size_t)mm * Cn + n0 + tn4] = ob;
    }
}

// ---------------------------------------------------------------- K8a: rfw fp32 [co][ci][tap] -> bf16 [tap][co][ci]
__global__ __launch_bounds__(256) void k_cvt_rfw(const float* __restrict__ rfw,
                                                 u16* __restrict__ wcv) {
    int g = blockIdx.x * 256 + threadIdx.x;  // dest index
    if (g >= Cn * Cn * 9) return;
    int tap = g / (Cn * Cn);
    int rem = g - tap * (Cn * Cn);
    int co = rem / Cn, ci = rem - co * Cn;
    wcv[g] = f2bf(rfw[((size_t)co * Cn + ci) * 9 + tap]);
}

// ---------------------------------------------------------------- K8: conv3x3 + BN + ReLU, bf16 MFMA implicit GEMM
// BM=128 spatial (2 image rows), BN=64 co, ci-block=32. 4 waves, wave = 32 rows x 64 co.
__global__ __launch_bounds__(256) void k_conv3(const u16* __restrict__ t2bf,
                                               const u16* __restrict__ wcv,
                                               const float* __restrict__ rfb,
                                               const float* __restrict__ bnw,
                                               const float* __restrict__ bnb,
                                               const float* __restrict__ bnm,
                                               const float* __restrict__ bnv,
                                               float* __restrict__ out) {
    // LDS: input tile 4 rows x 66 cols x 32 ci (pad->40), weights 9 taps x 64 co x 32 ci (pad->40)
    __shared__ __align__(16) u16 in_s[4 * 66 * 40];   // 21,120 B
    __shared__ __align__(16) u16 w_s[9 * 64 * 40];    // 46,080 B
    int mt = blockIdx.x;            // 0..127 : spatial tile (128 positions = 2 rows)
    int n0 = blockIdx.y << 6;       // co tile base
    int b = mt >> 5;
    int h0 = (mt & 31) << 1;
    int hw0 = h0 << 6;
    int tid = threadIdx.x;
    int wid = tid >> 6, lane = tid & 63;
    int lrow = lane & 15, lk8 = (lane >> 4) << 3, l4 = (lane >> 4) << 2;

    // zero the halo pad columns (col index 0 and 65) once
    for (int idx = tid; idx < 4 * 40; idx += 256) {
        int rl = idx / 40, k = idx - rl * 40;
        in_s[(rl * 66 + 0) * 40 + k] = 0;
        in_s[(rl * 66 + 65) * 40 + k] = 0;
    }

    // per-wave A/B base element offsets
    int s0 = wid * 32 + lrow;           // mf=0 spatial row
    int s1 = s0 + 16;                   // mf=1
    int abase0 = ((s0 >> 6) * 66 + (s0 & 63)) * 40 + lk8;
    int abase1 = ((s1 >> 6) * 66 + (s1 & 63)) * 40 + lk8;
    int bbase = lrow * 40 + lk8;

    f32x4 acc[2][4];
#pragma unroll
    for (int i = 0; i < 2; ++i)
#pragma unroll
        for (int j = 0; j < 4; ++j) acc[i][j] = (f32x4){0.f, 0.f, 0.f, 0.f};

    int wq = tid >> 2, cq = (tid & 3) << 3;  // staging coords: w (0..63), ci-oct
    for (int ci0 = 0; ci0 < Cn; ci0 += 32) {
        __syncthreads();
        // stage input rows h0-1 .. h0+2 (zero pad outside image)
#pragma unroll
        for (int rl = 0; rl < 4; ++rl) {
            int gr = h0 - 1 + rl;
            uint4 v = make_uint4(0u, 0u, 0u, 0u);
            if (gr >= 0 && gr < Hn)
                v = *(const uint4*)&t2bf[(size_t)((b << 12) + (gr << 6) + wq) * Cn + ci0 + cq];
            *(uint4*)&in_s[(rl * 66 + wq + 1) * 40 + cq] = v;
        }
        // stage weights: 9 taps x 64 co x 32 ci
#pragma unroll
        for (int tap = 0; tap < 9; ++tap) {
            int co = tid >> 2;  // 0..63
            uint4 v = *(const uint4*)&wcv[((size_t)tap * Cn + n0 + co) * Cn + ci0 + cq];
            *(uint4*)&w_s[(tap * 64 + co) * 40 + cq] = v;
        }
        __syncthreads();
#pragma unroll
        for (int kh = 0; kh < 3; ++kh) {
#pragma unroll
            for (int kw = 0; kw < 3; ++kw) {
                int aoff = (kh * 66 + kw) * 40;
                bf16x8 a0 = *(const bf16x8*)&in_s[abase0 + aoff];
                bf16x8 a1 = *(const bf16x8*)&in_s[abase1 + aoff];
                int boff = (kh * 3 + kw) * 2560;
#pragma unroll
                for (int nf = 0; nf < 4; ++nf) {
                    bf16x8 bb = *(const bf16x8*)&w_s[bbase + nf * 640 + boff];
                    acc[0][nf] = __builtin_amdgcn_mfma_f32_16x16x32_bf16(a0, bb, acc[0][nf], 0, 0, 0);
                    acc[1][nf] = __builtin_amdgcn_mfma_f32_16x16x32_bf16(a1, bb, acc[1][nf], 0, 0, 0);
                }
            }
        }
    }
    // epilogue: BN(eval) + ReLU, store NCHW fp32
#pragma unroll
    for (int nf = 0; nf < 4; ++nf) {
        int co = n0 + nf * 16 + lrow;
        float sc = bnw[co] * rsqrtf(bnv[co] + EPSf);
        float sf = (rfb[co] - bnm[co]) * sc + bnb[co];
        size_t obase = ((size_t)(b * Cn + co) << 12) + hw0;
#pragma unroll
        for (int mf = 0; mf < 2; ++mf) {
            int sb = wid * 32 + mf * 16 + l4;
            float4 o;
            o.x = fmaxf(acc[mf][nf][0] * sc + sf, 0.f);
            o.y = fmaxf(acc[mf][nf][1] * sc + sf, 0.f);
            o.z = fmaxf(acc[mf][nf][2] * sc + sf, 0.f);
            o.w = fmaxf(acc[mf][nf][3] * sc + sf, 0.f);
            *(float4*)&out[obase + sb] = o;
        }
    }
}

// ----------------------------------------------------------------
extern "C" void kernel_launch(void* const* d_in, const int* in_sizes, int n_in,
                              void* d_out, int out_size, void* d_ws, size_t ws_size,
                              hipStream_t stream) {
    const float* x    = (const float*)d_in[0];
    const float* lnw  = (const float*)d_in[1];
    const float* lnb  = (const float*)d_in[2];
    const float* inpw = (const float*)d_in[3];
    const float* cw   = (const float*)d_in[4];
    const float* cb   = (const float*)d_in[5];
    const float* xpw  = (const float*)d_in[6];
    const float* dtw  = (const float*)d_in[7];
    const float* dtb  = (const float*)d_in[8];
    const float* alog = (const float*)d_in[9];
    const float* Dp   = (const float*)d_in[10];
    const float* Wo   = (const float*)d_in[11];
    const float* rfw  = (const float*)d_in[12];
    const float* rfb  = (const float*)d_in[13];
    const float* bnw  = (const float*)d_in[14];
    const float* bnb  = (const float*)d_in[15];
    const float* bnm  = (const float*)d_in[16];
    const float* bnv  = (const float*)d_in[17];

    float* ws    = (float*)d_ws;
    float* tn    = ws;              // 3,145,728 floats; later reused as t2bf (bf16)
    float* xz    = ws + 3145728;    // 12,582,912
    float* xt    = ws + 15728640;   // 6,291,456
    float* dbl   = ws + 22020096;   // 720,896
    float* delta = ws + 22740992;   // 6,291,456 ; tail reused as wcv (bf16) after k_scan
    float* ysb   = ws + 29032448;   // 6,291,456  (end: 35,323,904 floats)
    u16* t2bf    = (u16*)tn;        // 16384*192 bf16 = 6.3 MB (tn dead after in_proj)
    u16* wcv     = (u16*)delta;     // 331,776 bf16 (delta dead after k_scan)

    k_ln<<<Bn * (Ln / 64), 256, 0, stream>>>(x, lnw, lnb, tn);
    k_gemm<Cn><<<dim3((Bn * Ln) / 64, E2 / 64), 256, 0, stream>>>(tn, inpw, xz, E2);
    k_conv1d<<<(Bn * Ln * (DIn / 4)) / 256, 256, 0, stream>>>(xz, cw, cb, xt);
    k_xproj<<<(Bn * Ln) / 64, 256, 0, stream>>>(xt, xpw, dbl);
    k_dtproj<<<(Bn * Ln) / 64, 256, 0, stream>>>(dbl, dtw, dtb, delta);
    k_scan<<<Bn * (DIn / 16), 256, 0, stream>>>(delta, xt, dbl, alog, ysb);
    k_gate<<<dim3((Bn * Ln) / 64, Cn / 64), 256, 0, stream>>>(ysb, xt, xz, Dp, Wo, x, t2bf);
    k_cvt_rfw<<<(Cn * Cn * 9 + 255) / 256, 256, 0, stream>>>(rfw, wcv);
    k_conv3<<<dim3(128, Cn / 64), 256, 0, stream>>>(t2bf, wcv, rfb, bnw, bnb, bnm, bnv,
                                                    (float*)d_out);
}

// Round 3
// 381.588 us; speedup vs baseline: 3.3650x; 2.0508x over previous
//
#include <hip/hip_runtime.h>

// MambaSkipConnection: B=4, C=192, H=W=64 (L=4096), DI=384, N=16, RK=12, DCONV=4
// Round 3: selective scan -> 3-pass chunked parallel scan (64 chunks x 64 steps).
// conv3x3 stays bf16 MFMA. GEMMs still fp32 (next round).
// Workspace usage unchanged: 35,323,904 floats = 141.3 MB.

#define Bn 4
#define Cn 192
#define Hn 64
#define Wn 64
#define Ln 4096
#define DIn 384
#define Nst 16
#define RK 12
#define E2 768
#define NCn 64
#define EPSf 1e-5f

typedef __bf16 bf16x8 __attribute__((ext_vector_type(8)));
typedef float f32x4 __attribute__((ext_vector_type(4)));
typedef unsigned short u16;
typedef unsigned int u32;

static __device__ __forceinline__ float sigmoidf_(float v) {
    return 1.f / (1.f + __expf(-v));
}
static __device__ __forceinline__ float softplusf_(float v) {
    return v > 20.f ? v : log1pf(__expf(v));
}
static __device__ __forceinline__ u16 f2bf(float f) {
    u32 u = __float_as_uint(f);
    u32 r = (u + 0x7FFFu + ((u >> 16) & 1u)) >> 16;
    return (u16)r;
}

// ---------------------------------------------------------------- K1: LayerNorm
__global__ __launch_bounds__(256) void k_ln(const float* __restrict__ x,
                                            const float* __restrict__ lnw,
                                            const float* __restrict__ lnb,
                                            float* __restrict__ tn) {
    __shared__ float tile[Cn][65];
    __shared__ float red[2][4][64];
    __shared__ float mean_s[64], rstd_s[64];
    int b = blockIdx.x >> 6;
    int l0 = (blockIdx.x & 63) << 6;
    int tid = threadIdx.x;
    for (int idx = tid; idx < Cn * 64; idx += 256) {
        int c = idx >> 6, ll = idx & 63;
        tile[c][ll] = x[((size_t)(b * Cn + c) << 12) + l0 + ll];
    }
    __syncthreads();
    int ll = tid & 63, grp = tid >> 6;
    float s = 0.f, s2 = 0.f;
    for (int c = grp * 48; c < grp * 48 + 48; ++c) {
        float v = tile[c][ll];
        s += v; s2 += v * v;
    }
    red[0][grp][ll] = s; red[1][grp][ll] = s2;
    __syncthreads();
    if (tid < 64) {
        float m = red[0][0][tid] + red[0][1][tid] + red[0][2][tid] + red[0][3][tid];
        float q = red[1][0][tid] + red[1][1][tid] + red[1][2][tid] + red[1][3][tid];
        m *= (1.f / Cn);
        float var = q * (1.f / Cn) - m * m;
        mean_s[tid] = m;
        rstd_s[tid] = rsqrtf(var + EPSf);
    }
    __syncthreads();
    for (int idx = tid; idx < 64 * Cn; idx += 256) {
        int t = idx / Cn, c = idx - t * Cn;
        float v = (tile[c][t] - mean_s[t]) * rstd_s[t] * lnw[c] + lnb[c];
        tn[(size_t)(b * Ln + l0 + t) * Cn + c] = v;
    }
}

// ---------------------------------------------------------------- K2: tiled GEMM (fp32)
template <int K>
__global__ __launch_bounds__(256) void k_gemm(const float* __restrict__ A,
                                              const float* __restrict__ Wt,
                                              float* __restrict__ out, int Nn) {
    __shared__ __align__(16) float As[16][68];
    __shared__ __align__(16) float Ws[16][68];
    int m0 = blockIdx.x << 6, n0 = blockIdx.y << 6;
    int tid = threadIdx.x;
    int lm = tid >> 2, lk = (tid & 3) << 2;
    int tm = (tid >> 4) << 2, tn4 = (tid & 15) << 2;
    float acc[4][4] = {};
    for (int k0 = 0; k0 < K; k0 += 16) {
        float4 a4 = *(const float4*)&A[(size_t)(m0 + lm) * K + k0 + lk];
        float4 w4 = *(const float4*)&Wt[(size_t)(n0 + lm) * K + k0 + lk];
        As[lk + 0][lm] = a4.x; As[lk + 1][lm] = a4.y; As[lk + 2][lm] = a4.z; As[lk + 3][lm] = a4.w;
        Ws[lk + 0][lm] = w4.x; Ws[lk + 1][lm] = w4.y; Ws[lk + 2][lm] = w4.z; Ws[lk + 3][lm] = w4.w;
        __syncthreads();
#pragma unroll
        for (int kk = 0; kk < 16; ++kk) {
            float4 av = *(const float4*)&As[kk][tm];
            float4 wv = *(const float4*)&Ws[kk][tn4];
            acc[0][0] = fmaf(av.x, wv.x, acc[0][0]);
            acc[0][1] = fmaf(av.x, wv.y, acc[0][1]);
            acc[0][2] = fmaf(av.x, wv.z, acc[0][2]);
            acc[0][3] = fmaf(av.x, wv.w, acc[0][3]);
            acc[1][0] = fmaf(av.y, wv.x, acc[1][0]);
            acc[1][1] = fmaf(av.y, wv.y, acc[1][1]);
            acc[1][2] = fmaf(av.y, wv.z, acc[1][2]);
            acc[1][3] = fmaf(av.y, wv.w, acc[1][3]);
            acc[2][0] = fmaf(av.z, wv.x, acc[2][0]);
            acc[2][1] = fmaf(av.z, wv.y, acc[2][1]);
            acc[2][2] = fmaf(av.z, wv.z, acc[2][2]);
            acc[2][3] = fmaf(av.z, wv.w, acc[2][3]);
            acc[3][0] = fmaf(av.w, wv.x, acc[3][0]);
            acc[3][1] = fmaf(av.w, wv.y, acc[3][1]);
            acc[3][2] = fmaf(av.w, wv.z, acc[3][2]);
            acc[3][3] = fmaf(av.w, wv.w, acc[3][3]);
        }
        __syncthreads();
    }
#pragma unroll
    for (int i = 0; i < 4; ++i) {
        float4 o;
        o.x = acc[i][0]; o.y = acc[i][1]; o.z = acc[i][2]; o.w = acc[i][3];
        *(float4*)&out[(size_t)(m0 + tm + i) * Nn + n0 + tn4] = o;
    }
}

// ---------------------------------------------------------------- K3: causal depthwise conv1d + SiLU
__global__ __launch_bounds__(256) void k_conv1d(const float* __restrict__ xz,
                                                const float* __restrict__ cw,
                                                const float* __restrict__ cb,
                                                float* __restrict__ xt) {
    int g = blockIdx.x * 256 + threadIdx.x;
    int m = g / 96, dq = g - m * 96;
    int d = dq << 2;
    int l = m & (Ln - 1);
    float w_[4][4];
    *(float4*)&w_[0][0] = *(const float4*)&cw[(d + 0) << 2];
    *(float4*)&w_[1][0] = *(const float4*)&cw[(d + 1) << 2];
    *(float4*)&w_[2][0] = *(const float4*)&cw[(d + 2) << 2];
    *(float4*)&w_[3][0] = *(const float4*)&cw[(d + 3) << 2];
    float4 bv = *(const float4*)&cb[d];
    float o_[4] = {bv.x, bv.y, bv.z, bv.w};
    const float* base = xz + (size_t)m * E2 + d;
#pragma unroll
    for (int j = 0; j < 4; ++j) {
        if (l >= j) {
            float4 in4 = *(const float4*)(base - (size_t)j * E2);
            o_[0] += in4.x * w_[0][3 - j];
            o_[1] += in4.y * w_[1][3 - j];
            o_[2] += in4.z * w_[2][3 - j];
            o_[3] += in4.w * w_[3][3 - j];
        }
    }
    float4 r;
    r.x = o_[0] * sigmoidf_(o_[0]);
    r.y = o_[1] * sigmoidf_(o_[1]);
    r.z = o_[2] * sigmoidf_(o_[2]);
    r.w = o_[3] * sigmoidf_(o_[3]);
    *(float4*)&xt[(size_t)m * DIn + d] = r;
}

// ---------------------------------------------------------------- K4: x_proj (N=44)
__global__ __launch_bounds__(256) void k_xproj(const float* __restrict__ xt,
                                               const float* __restrict__ xpw,
                                               float* __restrict__ dbl) {
    __shared__ float As[64][69];
    __shared__ float Ws_[64][45];
    int m0 = blockIdx.x << 6, tid = threadIdx.x;
    int tok = tid & 63, nset = tid >> 6;
    float acc[11] = {};
    for (int k0 = 0; k0 < DIn; k0 += 64) {
        for (int idx = tid; idx < 64 * 64; idx += 256)
            As[idx >> 6][idx & 63] = xt[(size_t)(m0 + (idx >> 6)) * DIn + k0 + (idx & 63)];
        for (int idx = tid; idx < 44 * 64; idx += 256) {
            int n = idx >> 6, k = idx & 63;
            Ws_[k][n] = xpw[(size_t)n * DIn + k0 + k];
        }
        __syncthreads();
        for (int k = 0; k < 64; ++k) {
            float a = As[tok][k];
#pragma unroll
            for (int j = 0; j < 11; ++j)
                acc[j] = fmaf(a, Ws_[k][nset * 11 + j], acc[j]);
        }
        __syncthreads();
    }
#pragma unroll
    for (int j = 0; j < 11; ++j)
        dbl[(size_t)(m0 + tok) * 44 + nset * 11 + j] = acc[j];
}

// ---------------------------------------------------------------- K5: dt_proj + softplus
__global__ __launch_bounds__(256) void k_dtproj(const float* __restrict__ dbl,
                                                const float* __restrict__ dtw,
                                                const float* __restrict__ dtb,
                                                float* __restrict__ delta) {
    __shared__ float dts[64][13];
    __shared__ float wls[RK][DIn];
    __shared__ float bls[DIn];
    int m0 = blockIdx.x << 6, tid = threadIdx.x;
    for (int idx = tid; idx < 64 * RK; idx += 256) {
        int t = idx / RK, r = idx - t * RK;
        dts[t][r] = dbl[(size_t)(m0 + t) * 44 + r];
    }
    for (int idx = tid; idx < DIn * RK; idx += 256) {
        int dd = idx / RK, r = idx - dd * RK;
        wls[r][dd] = dtw[idx];
    }
    for (int idx = tid; idx < DIn; idx += 256) bls[idx] = dtb[idx];
    __syncthreads();
    for (int i = 0; i < 96; ++i) {
        int idx = tid + (i << 8);
        int t = idx / DIn, dd = idx - t * DIn;
        float acc = bls[dd];
#pragma unroll
        for (int r = 0; r < RK; ++r) acc = fmaf(dts[t][r], wls[r][dd], acc);
        delta[(size_t)(m0 + t) * DIn + dd] = softplusf_(acc);
    }
}

// ---------------------------------------------------------------- K6a: scan pass 1 — chunk summaries
// block: (dg, c, b); 256 threads = 16 d x 16 n. Summary layout [b][c][d][n].
__global__ __launch_bounds__(256) void k_scan1(const float* __restrict__ delta,
                                               const float* __restrict__ xt,
                                               const float* __restrict__ dbl,
                                               const float* __restrict__ alog,
                                               float* __restrict__ chunkA,
                                               float* __restrict__ chunkH) {
    __shared__ float ds_d[16][17], ds_u[16][17], ds_bt[16][17];
    int dg = blockIdx.x, c = blockIdx.y, b = blockIdx.z;
    int tid = threadIdx.x, ch = tid >> 4, n = tid & 15;
    int d = dg * 16 + ch;
    float Av = -__expf(alog[d * Nst + n]);
    float h = 0.f, ap = 1.f;
    int trow = tid >> 4, dd = tid & 15;
    for (int sub = 0; sub < 4; ++sub) {
        int row = b * Ln + c * 64 + sub * 16 + trow;
        ds_d[trow][dd] = delta[(size_t)row * DIn + dg * 16 + dd];
        ds_u[trow][dd] = xt[(size_t)row * DIn + dg * 16 + dd];
        ds_bt[trow][dd] = dbl[(size_t)row * 44 + 12 + dd];
        __syncthreads();
#pragma unroll
        for (int tt = 0; tt < 16; ++tt) {
            float de = ds_d[tt][ch], uu = ds_u[tt][ch], bb = ds_bt[tt][n];
            float a = __expf(de * Av);
            ap *= a;
            h = fmaf(a, h, de * uu * bb);
        }
        __syncthreads();
    }
    size_t base = (size_t)(b * NCn + c) * (DIn * Nst) + dg * 256;
    chunkA[base + tid] = ap;
    chunkH[base + tid] = h;
}

// ---------------------------------------------------------------- K6b: scan pass 1.5 — chunk-start states
__global__ __launch_bounds__(256) void k_scan15(const float* __restrict__ chunkA,
                                                const float* __restrict__ chunkH,
                                                float* __restrict__ hstart) {
    int dg = blockIdx.x, b = blockIdx.y;
    int tid = threadIdx.x;
    size_t off = (size_t)b * NCn * (DIn * Nst) + dg * 256 + tid;
    float h = 0.f;
    for (int c0 = 0; c0 < NCn; c0 += 8) {
        float Ar[8], Hr[8];
#pragma unroll
        for (int j = 0; j < 8; ++j) {
            Ar[j] = chunkA[off + (size_t)(c0 + j) * (DIn * Nst)];
            Hr[j] = chunkH[off + (size_t)(c0 + j) * (DIn * Nst)];
        }
#pragma unroll
        for (int j = 0; j < 8; ++j) {
            hstart[off + (size_t)(c0 + j) * (DIn * Nst)] = h;
            h = fmaf(Ar[j], h, Hr[j]);
        }
    }
}

// ---------------------------------------------------------------- K6c: scan pass 2 — per-chunk scan + y
__global__ __launch_bounds__(256) void k_scan2(const float* __restrict__ delta,
                                               const float* __restrict__ xt,
                                               const float* __restrict__ dbl,
                                               const float* __restrict__ alog,
                                               const float* __restrict__ hstart,
                                               float* __restrict__ ys) {
    __shared__ float ds_d[16][17], ds_u[16][17], ds_bt[16][17], ds_ct[16][17];
    __shared__ float pbuf[16][16][17];
    int dg = blockIdx.x, c = blockIdx.y, b = blockIdx.z;
    int tid = threadIdx.x, ch = tid >> 4, n = tid & 15;
    int d = dg * 16 + ch;
    float Av = -__expf(alog[d * Nst + n]);
    size_t base = (size_t)(b * NCn + c) * (DIn * Nst) + dg * 256;
    float h = hstart[base + tid];
    int trow = tid >> 4, dd = tid & 15;
    for (int sub = 0; sub < 4; ++sub) {
        int row = b * Ln + c * 64 + sub * 16 + trow;
        ds_d[trow][dd] = delta[(size_t)row * DIn + dg * 16 + dd];
        ds_u[trow][dd] = xt[(size_t)row * DIn + dg * 16 + dd];
        ds_bt[trow][dd] = dbl[(size_t)row * 44 + 12 + dd];
        ds_ct[trow][dd] = dbl[(size_t)row * 44 + 28 + dd];
        __syncthreads();
#pragma unroll
        for (int tt = 0; tt < 16; ++tt) {
            float de = ds_d[tt][ch], uu = ds_u[tt][ch];
            float a = __expf(de * Av);
            h = fmaf(a, h, de * uu * ds_bt[tt][n]);
            pbuf[tt][ch][n] = h * ds_ct[tt][n];
        }
        __syncthreads();
        float s = 0.f;
#pragma unroll
        for (int q = 0; q < 16; ++q) s += pbuf[trow][dd][q];
        ys[(size_t)row * DIn + dg * 16 + dd] = s;
    }
}

// ---------------------------------------------------------------- K7: gate + out_proj + residual
__global__ __launch_bounds__(256) void k_gate(const float* __restrict__ ys,
                                              const float* __restrict__ xt,
                                              const float* __restrict__ xz,
                                              const float* __restrict__ Dp,
                                              const float* __restrict__ Wo,
                                              const float* __restrict__ x,
                                              u16* __restrict__ t2bf) {
    __shared__ __align__(16) float As[16][68];
    __shared__ __align__(16) float Ws[16][68];
    int m0 = blockIdx.x << 6, n0 = blockIdx.y << 6;
    int tid = threadIdx.x;
    int lm = tid >> 2, lk = (tid & 3) << 2;
    int tm = (tid >> 4) << 2, tn4 = (tid & 15) << 2;
    float acc[4][4] = {};
    for (int k0 = 0; k0 < DIn; k0 += 16) {
        size_t arow = (size_t)(m0 + lm) * DIn + k0 + lk;
        float4 y4 = *(const float4*)&ys[arow];
        float4 u4 = *(const float4*)&xt[arow];
        float4 z4 = *(const float4*)&xz[(size_t)(m0 + lm) * E2 + DIn + k0 + lk];
        float4 d4 = *(const float4*)&Dp[k0 + lk];
        As[lk + 0][lm] = (y4.x + u4.x * d4.x) * (z4.x * sigmoidf_(z4.x));
        As[lk + 1][lm] = (y4.y + u4.y * d4.y) * (z4.y * sigmoidf_(z4.y));
        As[lk + 2][lm] = (y4.z + u4.z * d4.z) * (z4.z * sigmoidf_(z4.z));
        As[lk + 3][lm] = (y4.w + u4.w * d4.w) * (z4.w * sigmoidf_(z4.w));
        float4 w4 = *(const float4*)&Wo[(size_t)(n0 + lm) * DIn + k0 + lk];
        Ws[lk + 0][lm] = w4.x; Ws[lk + 1][lm] = w4.y; Ws[lk + 2][lm] = w4.z; Ws[lk + 3][lm] = w4.w;
        __syncthreads();
#pragma unroll
        for (int kk = 0; kk < 16; ++kk) {
            float4 av = *(const float4*)&As[kk][tm];
            float4 wv = *(const float4*)&Ws[kk][tn4];
            acc[0][0] = fmaf(av.x, wv.x, acc[0][0]);
            acc[0][1] = fmaf(av.x, wv.y, acc[0][1]);
            acc[0][2] = fmaf(av.x, wv.z, acc[0][2]);
            acc[0][3] = fmaf(av.x, wv.w, acc[0][3]);
            acc[1][0] = fmaf(av.y, wv.x, acc[1][0]);
            acc[1][1] = fmaf(av.y, wv.y, acc[1][1]);
            acc[1][2] = fmaf(av.y, wv.z, acc[1][2]);
            acc[1][3] = fmaf(av.y, wv.w, acc[1][3]);
            acc[2][0] = fmaf(av.z, wv.x, acc[2][0]);
            acc[2][1] = fmaf(av.z, wv.y, acc[2][1]);
            acc[2][2] = fmaf(av.z, wv.z, acc[2][2]);
            acc[2][3] = fmaf(av.z, wv.w, acc[2][3]);
            acc[3][0] = fmaf(av.w, wv.x, acc[3][0]);
            acc[3][1] = fmaf(av.w, wv.y, acc[3][1]);
            acc[3][2] = fmaf(av.w, wv.z, acc[3][2]);
            acc[3][3] = fmaf(av.w, wv.w, acc[3][3]);
        }
        __syncthreads();
    }
#pragma unroll
    for (int i = 0; i < 4; ++i) {
        int mm = m0 + tm + i;
        int b = mm >> 12, l = mm & 4095;
        float4 o;
        o.x = acc[i][0] + x[((size_t)(b * Cn + n0 + tn4 + 0) << 12) + l];
        o.y = acc[i][1] + x[((size_t)(b * Cn + n0 + tn4 + 1) << 12) + l];
        o.z = acc[i][2] + x[((size_t)(b * Cn + n0 + tn4 + 2) << 12) + l];
        o.w = acc[i][3] + x[((size_t)(b * Cn + n0 + tn4 + 3) << 12) + l];
        ushort4 ob;
        ob.x = f2bf(o.x); ob.y = f2bf(o.y); ob.z = f2bf(o.z); ob.w = f2bf(o.w);
        *(ushort4*)&t2bf[(size_t)mm * Cn + n0 + tn4] = ob;
    }
}

// ---------------------------------------------------------------- K8a: rfw fp32 [co][ci][tap] -> bf16 [tap][co][ci]
__global__ __launch_bounds__(256) void k_cvt_rfw(const float* __restrict__ rfw,
                                                 u16* __restrict__ wcv) {
    int g = blockIdx.x * 256 + threadIdx.x;
    if (g >= Cn * Cn * 9) return;
    int tap = g / (Cn * Cn);
    int rem = g - tap * (Cn * Cn);
    int co = rem / Cn, ci = rem - co * Cn;
    wcv[g] = f2bf(rfw[((size_t)co * Cn + ci) * 9 + tap]);
}

// ---------------------------------------------------------------- K8: conv3x3 + BN + ReLU, bf16 MFMA implicit GEMM
__global__ __launch_bounds__(256) void k_conv3(const u16* __restrict__ t2bf,
                                               const u16* __restrict__ wcv,
                                               const float* __restrict__ rfb,
                                               const float* __restrict__ bnw,
                                               const float* __restrict__ bnb,
                                               const float* __restrict__ bnm,
                                               const float* __restrict__ bnv,
                                               float* __restrict__ out) {
    __shared__ __align__(16) u16 in_s[4 * 66 * 40];
    __shared__ __align__(16) u16 w_s[9 * 64 * 40];
    int mt = blockIdx.x;
    int n0 = blockIdx.y << 6;
    int b = mt >> 5;
    int h0 = (mt & 31) << 1;
    int hw0 = h0 << 6;
    int tid = threadIdx.x;
    int wid = tid >> 6, lane = tid & 63;
    int lrow = lane & 15, lk8 = (lane >> 4) << 3, l4 = (lane >> 4) << 2;

    for (int idx = tid; idx < 4 * 40; idx += 256) {
        int rl = idx / 40, k = idx - rl * 40;
        in_s[(rl * 66 + 0) * 40 + k] = 0;
        in_s[(rl * 66 + 65) * 40 + k] = 0;
    }

    int s0 = wid * 32 + lrow;
    int s1 = s0 + 16;
    int abase0 = ((s0 >> 6) * 66 + (s0 & 63)) * 40 + lk8;
    int abase1 = ((s1 >> 6) * 66 + (s1 & 63)) * 40 + lk8;
    int bbase = lrow * 40 + lk8;

    f32x4 acc[2][4];
#pragma unroll
    for (int i = 0; i < 2; ++i)
#pragma unroll
        for (int j = 0; j < 4; ++j) acc[i][j] = (f32x4){0.f, 0.f, 0.f, 0.f};

    int wq = tid >> 2, cq = (tid & 3) << 3;
    for (int ci0 = 0; ci0 < Cn; ci0 += 32) {
        __syncthreads();
#pragma unroll
        for (int rl = 0; rl < 4; ++rl) {
            int gr = h0 - 1 + rl;
            uint4 v = make_uint4(0u, 0u, 0u, 0u);
            if (gr >= 0 && gr < Hn)
                v = *(const uint4*)&t2bf[(size_t)((b << 12) + (gr << 6) + wq) * Cn + ci0 + cq];
            *(uint4*)&in_s[(rl * 66 + wq + 1) * 40 + cq] = v;
        }
#pragma unroll
        for (int tap = 0; tap < 9; ++tap) {
            int co = tid >> 2;
            uint4 v = *(const uint4*)&wcv[((size_t)tap * Cn + n0 + co) * Cn + ci0 + cq];
            *(uint4*)&w_s[(tap * 64 + co) * 40 + cq] = v;
        }
        __syncthreads();
#pragma unroll
        for (int kh = 0; kh < 3; ++kh) {
#pragma unroll
            for (int kw = 0; kw < 3; ++kw) {
                int aoff = (kh * 66 + kw) * 40;
                bf16x8 a0 = *(const bf16x8*)&in_s[abase0 + aoff];
                bf16x8 a1 = *(const bf16x8*)&in_s[abase1 + aoff];
                int boff = (kh * 3 + kw) * 2560;
#pragma unroll
                for (int nf = 0; nf < 4; ++nf) {
                    bf16x8 bb = *(const bf16x8*)&w_s[bbase + nf * 640 + boff];
                    acc[0][nf] = __builtin_amdgcn_mfma_f32_16x16x32_bf16(a0, bb, acc[0][nf], 0, 0, 0);
                    acc[1][nf] = __builtin_amdgcn_mfma_f32_16x16x32_bf16(a1, bb, acc[1][nf], 0, 0, 0);
                }
            }
        }
    }
#pragma unroll
    for (int nf = 0; nf < 4; ++nf) {
        int co = n0 + nf * 16 + lrow;
        float sc = bnw[co] * rsqrtf(bnv[co] + EPSf);
        float sf = (rfb[co] - bnm[co]) * sc + bnb[co];
        size_t obase = ((size_t)(b * Cn + co) << 12) + hw0;
#pragma unroll
        for (int mf = 0; mf < 2; ++mf) {
            int sb = wid * 32 + mf * 16 + l4;
            float4 o;
            o.x = fmaxf(acc[mf][nf][0] * sc + sf, 0.f);
            o.y = fmaxf(acc[mf][nf][1] * sc + sf, 0.f);
            o.z = fmaxf(acc[mf][nf][2] * sc + sf, 0.f);
            o.w = fmaxf(acc[mf][nf][3] * sc + sf, 0.f);
            *(float4*)&out[obase + sb] = o;
        }
    }
}

// ----------------------------------------------------------------
extern "C" void kernel_launch(void* const* d_in, const int* in_sizes, int n_in,
                              void* d_out, int out_size, void* d_ws, size_t ws_size,
                              hipStream_t stream) {
    const float* x    = (const float*)d_in[0];
    const float* lnw  = (const float*)d_in[1];
    const float* lnb  = (const float*)d_in[2];
    const float* inpw = (const float*)d_in[3];
    const float* cw   = (const float*)d_in[4];
    const float* cb   = (const float*)d_in[5];
    const float* xpw  = (const float*)d_in[6];
    const float* dtw  = (const float*)d_in[7];
    const float* dtb  = (const float*)d_in[8];
    const float* alog = (const float*)d_in[9];
    const float* Dp   = (const float*)d_in[10];
    const float* Wo   = (const float*)d_in[11];
    const float* rfw  = (const float*)d_in[12];
    const float* rfb  = (const float*)d_in[13];
    const float* bnw  = (const float*)d_in[14];
    const float* bnb  = (const float*)d_in[15];
    const float* bnm  = (const float*)d_in[16];
    const float* bnv  = (const float*)d_in[17];

    float* ws    = (float*)d_ws;
    float* tn    = ws;              // 3,145,728 floats; scratch: hstart (pass1.5/2), then t2bf
    float* xz    = ws + 3145728;    // 12,582,912
    float* xt    = ws + 15728640;   // 6,291,456
    float* dbl   = ws + 22020096;   // 720,896
    float* delta = ws + 22740992;   // 6,291,456 ; tail reused as wcv (bf16) after scan
    float* ysb   = ws + 29032448;   // 6,291,456 ; first half doubles as chunkA/chunkH pre-pass2
    u16* t2bf    = (u16*)tn;
    u16* wcv     = (u16*)delta;
    float* chunkA = ysb;                 // 1,572,864 floats (dead after k_scan15)
    float* chunkH = ysb + 1572864;       // 1,572,864 floats (dead after k_scan15)
    float* hstart = tn;                  // 1,572,864 floats (dead after k_scan2)

    k_ln<<<Bn * (Ln / 64), 256, 0, stream>>>(x, lnw, lnb, tn);
    k_gemm<Cn><<<dim3((Bn * Ln) / 64, E2 / 64), 256, 0, stream>>>(tn, inpw, xz, E2);
    k_conv1d<<<(Bn * Ln * (DIn / 4)) / 256, 256, 0, stream>>>(xz, cw, cb, xt);
    k_xproj<<<(Bn * Ln) / 64, 256, 0, stream>>>(xt, xpw, dbl);
    k_dtproj<<<(Bn * Ln) / 64, 256, 0, stream>>>(dbl, dtw, dtb, delta);
    k_scan1<<<dim3(DIn / 16, NCn, Bn), 256, 0, stream>>>(delta, xt, dbl, alog, chunkA, chunkH);
    k_scan15<<<dim3(DIn / 16, Bn), 256, 0, stream>>>(chunkA, chunkH, hstart);
    k_scan2<<<dim3(DIn / 16, NCn, Bn), 256, 0, stream>>>(delta, xt, dbl, alog, hstart, ysb);
    k_gate<<<dim3((Bn * Ln) / 64, Cn / 64), 256, 0, stream>>>(ysb, xt, xz, Dp, Wo, x, t2bf);
    k_cvt_rfw<<<(Cn * Cn * 9 + 255) / 256, 256, 0, stream>>>(rfw, wcv);
    k_conv3<<<dim3(128, Cn / 64), 256, 0, stream>>>(t2bf, wcv, rfb, bnw, bnb, bnm, bnv,
                                                    (float*)d_out);
}

// Round 4
// 281.374 us; speedup vs baseline: 4.5635x; 1.3562x over previous
//
#include <hip/hip_runtime.h>

// MambaSkipConnection: B=4, C=192, H=W=64 (L=4096), DI=384, N=16, RK=12, DCONV=4
// Round 4: all GEMMs (in_proj, x_proj, out_proj/gate) -> bf16 MFMA with on-the-fly
// fp32->bf16 weight conversion in LDS staging. Scan stays 3-pass fp32.
// Workspace usage unchanged: 35,323,904 floats = 141.3 MB.

#define Bn 4
#define Cn 192
#define Hn 64
#define Wn 64
#define Ln 4096
#define DIn 384
#define Nst 16
#define RK 12
#define E2 768
#define NCn 64
#define EPSf 1e-5f

typedef __bf16 bf16x8 __attribute__((ext_vector_type(8)));
typedef float f32x4 __attribute__((ext_vector_type(4)));
typedef unsigned short u16;
typedef unsigned int u32;

static __device__ __forceinline__ float sigmoidf_(float v) {
    return 1.f / (1.f + __expf(-v));
}
static __device__ __forceinline__ float softplusf_(float v) {
    return v > 20.f ? v : log1pf(__expf(v));
}
static __device__ __forceinline__ u16 f2bf(float f) {
    u32 u = __float_as_uint(f);
    u32 r = (u + 0x7FFFu + ((u >> 16) & 1u)) >> 16;
    return (u16)r;
}

// ---------------------------------------------------------------- K1: LayerNorm -> bf16 tokens
__global__ __launch_bounds__(256) void k_ln(const float* __restrict__ x,
                                            const float* __restrict__ lnw,
                                            const float* __restrict__ lnb,
                                            u16* __restrict__ tn_bf) {
    __shared__ float tile[Cn][65];
    __shared__ float red[2][4][64];
    __shared__ float mean_s[64], rstd_s[64];
    int b = blockIdx.x >> 6;
    int l0 = (blockIdx.x & 63) << 6;
    int tid = threadIdx.x;
    for (int idx = tid; idx < Cn * 64; idx += 256) {
        int c = idx >> 6, ll = idx & 63;
        tile[c][ll] = x[((size_t)(b * Cn + c) << 12) + l0 + ll];
    }
    __syncthreads();
    int ll = tid & 63, grp = tid >> 6;
    float s = 0.f, s2 = 0.f;
    for (int c = grp * 48; c < grp * 48 + 48; ++c) {
        float v = tile[c][ll];
        s += v; s2 += v * v;
    }
    red[0][grp][ll] = s; red[1][grp][ll] = s2;
    __syncthreads();
    if (tid < 64) {
        float m = red[0][0][tid] + red[0][1][tid] + red[0][2][tid] + red[0][3][tid];
        float q = red[1][0][tid] + red[1][1][tid] + red[1][2][tid] + red[1][3][tid];
        m *= (1.f / Cn);
        float var = q * (1.f / Cn) - m * m;
        mean_s[tid] = m;
        rstd_s[tid] = rsqrtf(var + EPSf);
    }
    __syncthreads();
    for (int idx = tid; idx < 64 * Cn; idx += 256) {
        int t = idx / Cn, c = idx - t * Cn;
        float v = (tile[c][t] - mean_s[t]) * rstd_s[t] * lnw[c] + lnb[c];
        tn_bf[(size_t)(b * Ln + l0 + t) * Cn + c] = f2bf(v);
    }
}

// ---------------------------------------------------------------- K2: generic bf16 MFMA GEMM
// A (M,K) bf16 rm; W (N,K) fp32 rm converted to bf16 during staging; out (M,LDO) fp32.
// 256 threads = 4 waves split along M; wave tile (BM/4) x BN.
template <int BM, int BN, int K, int BK, int NR, int LDO>
__global__ __launch_bounds__(256) void k_bgemm(const u16* __restrict__ A,
                                               const float* __restrict__ W,
                                               float* __restrict__ out) {
    constexpr int PK = BK + 8;
    constexpr int MF = BM / 64;
    constexpr int NF = BN / 16;
    constexpr int NCH = BK / 8;
    constexpr int NQ = BK / 4;
    __shared__ __align__(16) u16 As[BM * PK];
    __shared__ __align__(16) u16 Ws_[BN * PK];
    int m0 = blockIdx.x * BM, n0 = blockIdx.y * BN;
    int tid = threadIdx.x;
    int wid = tid >> 6, lane = tid & 63;
    int lrow = lane & 15, lk8 = (lane >> 4) << 3, rowq = lane >> 4;
    f32x4 acc[MF][NF];
#pragma unroll
    for (int i = 0; i < MF; ++i)
#pragma unroll
        for (int j = 0; j < NF; ++j) acc[i][j] = (f32x4){0.f, 0.f, 0.f, 0.f};
    for (int kt = 0; kt < K / BK; ++kt) {
        int k0 = kt * BK;
        for (int idx = tid; idx < BM * NCH; idx += 256) {
            int r = idx / NCH, c2 = idx - r * NCH;
            *(uint4*)&As[r * PK + c2 * 8] =
                *(const uint4*)&A[(size_t)(m0 + r) * K + k0 + c2 * 8];
        }
        for (int idx = tid; idx < BN * NQ; idx += 256) {
            int r = idx / NQ, q = idx - r * NQ;
            ushort4 o = make_ushort4(0, 0, 0, 0);
            if (NR == BN || r < NR) {
                float4 v = *(const float4*)&W[(size_t)(n0 + r) * K + k0 + q * 4];
                o.x = f2bf(v.x); o.y = f2bf(v.y); o.z = f2bf(v.z); o.w = f2bf(v.w);
            }
            *(ushort4*)&Ws_[r * PK + q * 4] = o;
        }
        __syncthreads();
#pragma unroll
        for (int ks = 0; ks < BK / 32; ++ks) {
            bf16x8 a[MF], bfr[NF];
#pragma unroll
            for (int mf = 0; mf < MF; ++mf)
                a[mf] = *(const bf16x8*)&As[(wid * (BM / 4) + mf * 16 + lrow) * PK + ks * 32 + lk8];
#pragma unroll
            for (int nf = 0; nf < NF; ++nf)
                bfr[nf] = *(const bf16x8*)&Ws_[(nf * 16 + lrow) * PK + ks * 32 + lk8];
#pragma unroll
            for (int mf = 0; mf < MF; ++mf)
#pragma unroll
                for (int nf = 0; nf < NF; ++nf)
                    acc[mf][nf] = __builtin_amdgcn_mfma_f32_16x16x32_bf16(a[mf], bfr[nf],
                                                                          acc[mf][nf], 0, 0, 0);
        }
        __syncthreads();
    }
#pragma unroll
    for (int mf = 0; mf < MF; ++mf)
#pragma unroll
        for (int nf = 0; nf < NF; ++nf) {
            int col = n0 + nf * 16 + lrow;
            if (NR != BN && col >= NR) continue;
            int rbase = m0 + wid * (BM / 4) + mf * 16 + rowq * 4;
#pragma unroll
            for (int r = 0; r < 4; ++r)
                out[(size_t)(rbase + r) * LDO + col] = acc[mf][nf][r];
        }
}

// ---------------------------------------------------------------- K3: causal depthwise conv1d + SiLU
// writes xt fp32 (for scan/gate) and xt_bf (for x_proj MFMA)
__global__ __launch_bounds__(256) void k_conv1d(const float* __restrict__ xz,
                                                const float* __restrict__ cw,
                                                const float* __restrict__ cb,
                                                float* __restrict__ xt,
                                                u16* __restrict__ xt_bf) {
    int g = blockIdx.x * 256 + threadIdx.x;
    int m = g / 96, dq = g - m * 96;
    int d = dq << 2;
    int l = m & (Ln - 1);
    float w_[4][4];
    *(float4*)&w_[0][0] = *(const float4*)&cw[(d + 0) << 2];
    *(float4*)&w_[1][0] = *(const float4*)&cw[(d + 1) << 2];
    *(float4*)&w_[2][0] = *(const float4*)&cw[(d + 2) << 2];
    *(float4*)&w_[3][0] = *(const float4*)&cw[(d + 3) << 2];
    float4 bv = *(const float4*)&cb[d];
    float o_[4] = {bv.x, bv.y, bv.z, bv.w};
    const float* base = xz + (size_t)m * E2 + d;
#pragma unroll
    for (int j = 0; j < 4; ++j) {
        if (l >= j) {
            float4 in4 = *(const float4*)(base - (size_t)j * E2);
            o_[0] += in4.x * w_[0][3 - j];
            o_[1] += in4.y * w_[1][3 - j];
            o_[2] += in4.z * w_[2][3 - j];
            o_[3] += in4.w * w_[3][3 - j];
        }
    }
    float4 r;
    r.x = o_[0] * sigmoidf_(o_[0]);
    r.y = o_[1] * sigmoidf_(o_[1]);
    r.z = o_[2] * sigmoidf_(o_[2]);
    r.w = o_[3] * sigmoidf_(o_[3]);
    *(float4*)&xt[(size_t)m * DIn + d] = r;
    ushort4 rb;
    rb.x = f2bf(r.x); rb.y = f2bf(r.y); rb.z = f2bf(r.z); rb.w = f2bf(r.w);
    *(ushort4*)&xt_bf[(size_t)m * DIn + d] = rb;
}

// ---------------------------------------------------------------- K5: dt_proj + softplus
__global__ __launch_bounds__(256) void k_dtproj(const float* __restrict__ dbl,
                                                const float* __restrict__ dtw,
                                                const float* __restrict__ dtb,
                                                float* __restrict__ delta) {
    __shared__ float dts[64][13];
    __shared__ float wls[RK][DIn];
    __shared__ float bls[DIn];
    int m0 = blockIdx.x << 6, tid = threadIdx.x;
    for (int idx = tid; idx < 64 * RK; idx += 256) {
        int t = idx / RK, r = idx - t * RK;
        dts[t][r] = dbl[(size_t)(m0 + t) * 44 + r];
    }
    for (int idx = tid; idx < DIn * RK; idx += 256) {
        int dd = idx / RK, r = idx - dd * RK;
        wls[r][dd] = dtw[idx];
    }
    for (int idx = tid; idx < DIn; idx += 256) bls[idx] = dtb[idx];
    __syncthreads();
    for (int i = 0; i < 96; ++i) {
        int idx = tid + (i << 8);
        int t = idx / DIn, dd = idx - t * DIn;
        float acc = bls[dd];
#pragma unroll
        for (int r = 0; r < RK; ++r) acc = fmaf(dts[t][r], wls[r][dd], acc);
        delta[(size_t)(m0 + t) * DIn + dd] = softplusf_(acc);
    }
}

// ---------------------------------------------------------------- K6a: scan pass 1 — chunk summaries
__global__ __launch_bounds__(256) void k_scan1(const float* __restrict__ delta,
                                               const float* __restrict__ xt,
                                               const float* __restrict__ dbl,
                                               const float* __restrict__ alog,
                                               float* __restrict__ chunkA,
                                               float* __restrict__ chunkH) {
    __shared__ float ds_d[16][17], ds_u[16][17], ds_bt[16][17];
    int dg = blockIdx.x, c = blockIdx.y, b = blockIdx.z;
    int tid = threadIdx.x, ch = tid >> 4, n = tid & 15;
    int d = dg * 16 + ch;
    float Av = -__expf(alog[d * Nst + n]);
    float h = 0.f, ap = 1.f;
    int trow = tid >> 4, dd = tid & 15;
    for (int sub = 0; sub < 4; ++sub) {
        int row = b * Ln + c * 64 + sub * 16 + trow;
        ds_d[trow][dd] = delta[(size_t)row * DIn + dg * 16 + dd];
        ds_u[trow][dd] = xt[(size_t)row * DIn + dg * 16 + dd];
        ds_bt[trow][dd] = dbl[(size_t)row * 44 + 12 + dd];
        __syncthreads();
#pragma unroll
        for (int tt = 0; tt < 16; ++tt) {
            float de = ds_d[tt][ch], uu = ds_u[tt][ch], bb = ds_bt[tt][n];
            float a = __expf(de * Av);
            ap *= a;
            h = fmaf(a, h, de * uu * bb);
        }
        __syncthreads();
    }
    size_t base = (size_t)(b * NCn + c) * (DIn * Nst) + dg * 256;
    chunkA[base + tid] = ap;
    chunkH[base + tid] = h;
}

// ---------------------------------------------------------------- K6b: scan pass 1.5 — chunk-start states
__global__ __launch_bounds__(256) void k_scan15(const float* __restrict__ chunkA,
                                                const float* __restrict__ chunkH,
                                                float* __restrict__ hstart) {
    int dg = blockIdx.x, b = blockIdx.y;
    int tid = threadIdx.x;
    size_t off = (size_t)b * NCn * (DIn * Nst) + dg * 256 + tid;
    float h = 0.f;
    for (int c0 = 0; c0 < NCn; c0 += 8) {
        float Ar[8], Hr[8];
#pragma unroll
        for (int j = 0; j < 8; ++j) {
            Ar[j] = chunkA[off + (size_t)(c0 + j) * (DIn * Nst)];
            Hr[j] = chunkH[off + (size_t)(c0 + j) * (DIn * Nst)];
        }
#pragma unroll
        for (int j = 0; j < 8; ++j) {
            hstart[off + (size_t)(c0 + j) * (DIn * Nst)] = h;
            h = fmaf(Ar[j], h, Hr[j]);
        }
    }
}

// ---------------------------------------------------------------- K6c: scan pass 2 — per-chunk scan + y
__global__ __launch_bounds__(256) void k_scan2(const float* __restrict__ delta,
                                               const float* __restrict__ xt,
                                               const float* __restrict__ dbl,
                                               const float* __restrict__ alog,
                                               const float* __restrict__ hstart,
                                               float* __restrict__ ys) {
    __shared__ float ds_d[16][17], ds_u[16][17], ds_bt[16][17], ds_ct[16][17];
    __shared__ float pbuf[16][16][17];
    int dg = blockIdx.x, c = blockIdx.y, b = blockIdx.z;
    int tid = threadIdx.x, ch = tid >> 4, n = tid & 15;
    int d = dg * 16 + ch;
    float Av = -__expf(alog[d * Nst + n]);
    size_t base = (size_t)(b * NCn + c) * (DIn * Nst) + dg * 256;
    float h = hstart[base + tid];
    int trow = tid >> 4, dd = tid & 15;
    for (int sub = 0; sub < 4; ++sub) {
        int row = b * Ln + c * 64 + sub * 16 + trow;
        ds_d[trow][dd] = delta[(size_t)row * DIn + dg * 16 + dd];
        ds_u[trow][dd] = xt[(size_t)row * DIn + dg * 16 + dd];
        ds_bt[trow][dd] = dbl[(size_t)row * 44 + 12 + dd];
        ds_ct[trow][dd] = dbl[(size_t)row * 44 + 28 + dd];
        __syncthreads();
#pragma unroll
        for (int tt = 0; tt < 16; ++tt) {
            float de = ds_d[tt][ch], uu = ds_u[tt][ch];
            float a = __expf(de * Av);
            h = fmaf(a, h, de * uu * ds_bt[tt][n]);
            pbuf[tt][ch][n] = h * ds_ct[tt][n];
        }
        __syncthreads();
        float s = 0.f;
#pragma unroll
        for (int q = 0; q < 16; ++q) s += pbuf[trow][dd][q];
        ys[(size_t)row * DIn + dg * 16 + dd] = s;
    }
}

// ---------------------------------------------------------------- K7: gate + out_proj (MFMA) + residual
// A = (ys + xt*D)*silu(z) computed fp32 -> bf16 in staging; epilogue adds residual, emits bf16 NHWC.
__global__ __launch_bounds__(256) void k_gate_mfma(const float* __restrict__ ys,
                                                   const float* __restrict__ xt,
                                                   const float* __restrict__ xz,
                                                   const float* __restrict__ Dp,
                                                   const float* __restrict__ Wo,
                                                   const float* __restrict__ x,
                                                   u16* __restrict__ t2bf) {
    constexpr int BM = 128, BN = 64, K = DIn, BK = 96;
    constexpr int PK = BK + 8;
    constexpr int NQ = BK / 4;
    __shared__ __align__(16) u16 As[BM * PK];
    __shared__ __align__(16) u16 Ws_[BN * PK];
    int m0 = blockIdx.x * BM, n0 = blockIdx.y * BN;
    int tid = threadIdx.x;
    int wid = tid >> 6, lane = tid & 63;
    int lrow = lane & 15, lk8 = (lane >> 4) << 3, rowq = lane >> 4;
    f32x4 acc[2][4];
#pragma unroll
    for (int i = 0; i < 2; ++i)
#pragma unroll
        for (int j = 0; j < 4; ++j) acc[i][j] = (f32x4){0.f, 0.f, 0.f, 0.f};
    for (int kt = 0; kt < K / BK; ++kt) {
        int k0 = kt * BK;
        for (int idx = tid; idx < BM * NQ; idx += 256) {
            int r = idx / NQ, q = idx - r * NQ;
            int m = m0 + r, dk = k0 + q * 4;
            float4 y4 = *(const float4*)&ys[(size_t)m * DIn + dk];
            float4 u4 = *(const float4*)&xt[(size_t)m * DIn + dk];
            float4 z4 = *(const float4*)&xz[(size_t)m * E2 + DIn + dk];
            float4 d4 = *(const float4*)&Dp[dk];
            ushort4 o;
            o.x = f2bf((y4.x + u4.x * d4.x) * (z4.x * sigmoidf_(z4.x)));
            o.y = f2bf((y4.y + u4.y * d4.y) * (z4.y * sigmoidf_(z4.y)));
            o.z = f2bf((y4.z + u4.z * d4.z) * (z4.z * sigmoidf_(z4.z)));
            o.w = f2bf((y4.w + u4.w * d4.w) * (z4.w * sigmoidf_(z4.w)));
            *(ushort4*)&As[r * PK + q * 4] = o;
        }
        for (int idx = tid; idx < BN * NQ; idx += 256) {
            int r = idx / NQ, q = idx - r * NQ;
            float4 v = *(const float4*)&Wo[(size_t)(n0 + r) * K + k0 + q * 4];
            ushort4 o;
            o.x = f2bf(v.x); o.y = f2bf(v.y); o.z = f2bf(v.z); o.w = f2bf(v.w);
            *(ushort4*)&Ws_[r * PK + q * 4] = o;
        }
        __syncthreads();
#pragma unroll
        for (int ks = 0; ks < BK / 32; ++ks) {
            bf16x8 a[2], bfr[4];
#pragma unroll
            for (int mf = 0; mf < 2; ++mf)
                a[mf] = *(const bf16x8*)&As[(wid * 32 + mf * 16 + lrow) * PK + ks * 32 + lk8];
#pragma unroll
            for (int nf = 0; nf < 4; ++nf)
                bfr[nf] = *(const bf16x8*)&Ws_[(nf * 16 + lrow) * PK + ks * 32 + lk8];
#pragma unroll
            for (int mf = 0; mf < 2; ++mf)
#pragma unroll
                for (int nf = 0; nf < 4; ++nf)
                    acc[mf][nf] = __builtin_amdgcn_mfma_f32_16x16x32_bf16(a[mf], bfr[nf],
                                                                          acc[mf][nf], 0, 0, 0);
        }
        __syncthreads();
    }
#pragma unroll
    for (int mf = 0; mf < 2; ++mf)
#pragma unroll
        for (int nf = 0; nf < 4; ++nf) {
            int col = n0 + nf * 16 + lrow;
            int rbase = m0 + wid * 32 + mf * 16 + rowq * 4;
#pragma unroll
            for (int r = 0; r < 4; ++r) {
                int m = rbase + r;
                int b = m >> 12, l = m & 4095;
                float v = acc[mf][nf][r] + x[((size_t)(b * Cn + col) << 12) + l];
                t2bf[(size_t)m * Cn + col] = f2bf(v);
            }
        }
}

// ---------------------------------------------------------------- K8a: rfw fp32 [co][ci][tap] -> bf16 [tap][co][ci]
__global__ __launch_bounds__(256) void k_cvt_rfw(const float* __restrict__ rfw,
                                                 u16* __restrict__ wcv) {
    int g = blockIdx.x * 256 + threadIdx.x;
    if (g >= Cn * Cn * 9) return;
    int tap = g / (Cn * Cn);
    int rem = g - tap * (Cn * Cn);
    int co = rem / Cn, ci = rem - co * Cn;
    wcv[g] = f2bf(rfw[((size_t)co * Cn + ci) * 9 + tap]);
}

// ---------------------------------------------------------------- K8: conv3x3 + BN + ReLU, bf16 MFMA implicit GEMM
__global__ __launch_bounds__(256) void k_conv3(const u16* __restrict__ t2bf,
                                               const u16* __restrict__ wcv,
                                               const float* __restrict__ rfb,
                                               const float* __restrict__ bnw,
                                               const float* __restrict__ bnb,
                                               const float* __restrict__ bnm,
                                               const float* __restrict__ bnv,
                                               float* __restrict__ out) {
    __shared__ __align__(16) u16 in_s[4 * 66 * 40];
    __shared__ __align__(16) u16 w_s[9 * 64 * 40];
    int mt = blockIdx.x;
    int n0 = blockIdx.y << 6;
    int b = mt >> 5;
    int h0 = (mt & 31) << 1;
    int hw0 = h0 << 6;
    int tid = threadIdx.x;
    int wid = tid >> 6, lane = tid & 63;
    int lrow = lane & 15, lk8 = (lane >> 4) << 3, l4 = (lane >> 4) << 2;

    for (int idx = tid; idx < 4 * 40; idx += 256) {
        int rl = idx / 40, k = idx - rl * 40;
        in_s[(rl * 66 + 0) * 40 + k] = 0;
        in_s[(rl * 66 + 65) * 40 + k] = 0;
    }

    int s0 = wid * 32 + lrow;
    int s1 = s0 + 16;
    int abase0 = ((s0 >> 6) * 66 + (s0 & 63)) * 40 + lk8;
    int abase1 = ((s1 >> 6) * 66 + (s1 & 63)) * 40 + lk8;
    int bbase = lrow * 40 + lk8;

    f32x4 acc[2][4];
#pragma unroll
    for (int i = 0; i < 2; ++i)
#pragma unroll
        for (int j = 0; j < 4; ++j) acc[i][j] = (f32x4){0.f, 0.f, 0.f, 0.f};

    int wq = tid >> 2, cq = (tid & 3) << 3;
    for (int ci0 = 0; ci0 < Cn; ci0 += 32) {
        __syncthreads();
#pragma unroll
        for (int rl = 0; rl < 4; ++rl) {
            int gr = h0 - 1 + rl;
            uint4 v = make_uint4(0u, 0u, 0u, 0u);
            if (gr >= 0 && gr < Hn)
                v = *(const uint4*)&t2bf[(size_t)((b << 12) + (gr << 6) + wq) * Cn + ci0 + cq];
            *(uint4*)&in_s[(rl * 66 + wq + 1) * 40 + cq] = v;
        }
#pragma unroll
        for (int tap = 0; tap < 9; ++tap) {
            int co = tid >> 2;
            uint4 v = *(const uint4*)&wcv[((size_t)tap * Cn + n0 + co) * Cn + ci0 + cq];
            *(uint4*)&w_s[(tap * 64 + co) * 40 + cq] = v;
        }
        __syncthreads();
#pragma unroll
        for (int kh = 0; kh < 3; ++kh) {
#pragma unroll
            for (int kw = 0; kw < 3; ++kw) {
                int aoff = (kh * 66 + kw) * 40;
                bf16x8 a0 = *(const bf16x8*)&in_s[abase0 + aoff];
                bf16x8 a1 = *(const bf16x8*)&in_s[abase1 + aoff];
                int boff = (kh * 3 + kw) * 2560;
#pragma unroll
                for (int nf = 0; nf < 4; ++nf) {
                    bf16x8 bb = *(const bf16x8*)&w_s[bbase + nf * 640 + boff];
                    acc[0][nf] = __builtin_amdgcn_mfma_f32_16x16x32_bf16(a0, bb, acc[0][nf], 0, 0, 0);
                    acc[1][nf] = __builtin_amdgcn_mfma_f32_16x16x32_bf16(a1, bb, acc[1][nf], 0, 0, 0);
                }
            }
        }
    }
#pragma unroll
    for (int nf = 0; nf < 4; ++nf) {
        int co = n0 + nf * 16 + lrow;
        float sc = bnw[co] * rsqrtf(bnv[co] + EPSf);
        float sf = (rfb[co] - bnm[co]) * sc + bnb[co];
        size_t obase = ((size_t)(b * Cn + co) << 12) + hw0;
#pragma unroll
        for (int mf = 0; mf < 2; ++mf) {
            int sb = wid * 32 + mf * 16 + l4;
            float4 o;
            o.x = fmaxf(acc[mf][nf][0] * sc + sf, 0.f);
            o.y = fmaxf(acc[mf][nf][1] * sc + sf, 0.f);
            o.z = fmaxf(acc[mf][nf][2] * sc + sf, 0.f);
            o.w = fmaxf(acc[mf][nf][3] * sc + sf, 0.f);
            *(float4*)&out[obase + sb] = o;
        }
    }
}

// ----------------------------------------------------------------
extern "C" void kernel_launch(void* const* d_in, const int* in_sizes, int n_in,
                              void* d_out, int out_size, void* d_ws, size_t ws_size,
                              hipStream_t stream) {
    const float* x    = (const float*)d_in[0];
    const float* lnw  = (const float*)d_in[1];
    const float* lnb  = (const float*)d_in[2];
    const float* inpw = (const float*)d_in[3];
    const float* cw   = (const float*)d_in[4];
    const float* cb   = (const float*)d_in[5];
    const float* xpw  = (const float*)d_in[6];
    const float* dtw  = (const float*)d_in[7];
    const float* dtb  = (const float*)d_in[8];
    const float* alog = (const float*)d_in[9];
    const float* Dp   = (const float*)d_in[10];
    const float* Wo   = (const float*)d_in[11];
    const float* rfw  = (const float*)d_in[12];
    const float* rfb  = (const float*)d_in[13];
    const float* bnw  = (const float*)d_in[14];
    const float* bnb  = (const float*)d_in[15];
    const float* bnm  = (const float*)d_in[16];
    const float* bnv  = (const float*)d_in[17];

    float* ws    = (float*)d_ws;
    // region map (floats):
    // [0 .. 1572864)        tn_bf (bf16, ln->inproj) -> t2bf (bf16, gate->conv3)
    // [1572864 .. 3145728)  hstart (scan15->scan2)
    // [3145728 .. 15728640) xz
    // [15728640..22020096)  xt (fp32)
    // [22020096..22740992)  dbl
    // [22740992..29032448)  xt_bf (bf16, conv1d->xproj) then delta (dtproj->scan2) then wcv
    // [29032448..35323904)  chunkA/chunkH (scan1->scan15) then ys (scan2->gate)
    u16* tn_bf   = (u16*)ws;
    float* hstart= ws + 1572864;
    float* xz    = ws + 3145728;
    float* xt    = ws + 15728640;
    float* dbl   = ws + 22020096;
    float* delta = ws + 22740992;
    float* ysb   = ws + 29032448;
    u16* t2bf    = (u16*)ws;
    u16* xt_bf   = (u16*)delta;
    u16* wcv     = (u16*)delta;
    float* chunkA = ysb;
    float* chunkH = ysb + 1572864;

    k_ln<<<Bn * (Ln / 64), 256, 0, stream>>>(x, lnw, lnb, tn_bf);
    k_bgemm<128, 64, Cn, 96, 64, E2><<<dim3((Bn * Ln) / 128, E2 / 64), 256, 0, stream>>>(
        tn_bf, inpw, xz);
    k_conv1d<<<(Bn * Ln * (DIn / 4)) / 256, 256, 0, stream>>>(xz, cw, cb, xt, xt_bf);
    k_bgemm<64, 48, DIn, 96, 44, 44><<<dim3((Bn * Ln) / 64, 1), 256, 0, stream>>>(
        xt_bf, xpw, dbl);
    k_dtproj<<<(Bn * Ln) / 64, 256, 0, stream>>>(dbl, dtw, dtb, delta);
    k_scan1<<<dim3(DIn / 16, NCn, Bn), 256, 0, stream>>>(delta, xt, dbl, alog, chunkA, chunkH);
    k_scan15<<<dim3(DIn / 16, Bn), 256, 0, stream>>>(chunkA, chunkH, hstart);
    k_scan2<<<dim3(DIn / 16, NCn, Bn), 256, 0, stream>>>(delta, xt, dbl, alog, hstart, ysb);
    k_gate_mfma<<<dim3((Bn * Ln) / 128, Cn / 64), 256, 0, stream>>>(ysb, xt, xz, Dp, Wo, x, t2bf);
    k_cvt_rfw<<<(Cn * Cn * 9 + 255) / 256, 256, 0, stream>>>(rfw, wcv);
    k_conv3<<<dim3(128, Cn / 64), 256, 0, stream>>>(t2bf, wcv, rfb, bnw, bnb, bnm, bnv,
                                                    (float*)d_out);
}

// Round 5
// 246.301 us; speedup vs baseline: 5.2134x; 1.1424x over previous
//
#include <hip/hip_runtime.h>

// MambaSkipConnection: B=4, C=192, H=W=64 (L=4096), DI=384, N=16, RK=12, DCONV=4
// Round 5: dt_proj fused into scan passes; gate fused into scan2 epilogue;
// bf16 intermediates (xz, xt, Agate) everywhere off the fp32-accumulate path.
// Workspace usage: 19,761,152 floats = 79.0 MB.

#define Bn 4
#define Cn 192
#define Hn 64
#define Wn 64
#define Ln 4096
#define DIn 384
#define Nst 16
#define RK 12
#define E2 768
#define NCn 64
#define EPSf 1e-5f

typedef __bf16 bf16x8 __attribute__((ext_vector_type(8)));
typedef float f32x4 __attribute__((ext_vector_type(4)));
typedef unsigned short u16;
typedef unsigned int u32;

static __device__ __forceinline__ float sigmoidf_(float v) {
    return 1.f / (1.f + __expf(-v));
}
static __device__ __forceinline__ float softplusf_(float v) {
    return v > 20.f ? v : log1pf(__expf(v));
}
static __device__ __forceinline__ u16 f2bf(float f) {
    u32 u = __float_as_uint(f);
    u32 r = (u + 0x7FFFu + ((u >> 16) & 1u)) >> 16;
    return (u16)r;
}
static __device__ __forceinline__ float bf2f(u16 v) {
    return __uint_as_float(((u32)v) << 16);
}

// ---------------------------------------------------------------- K1: LayerNorm -> bf16 tokens
__global__ __launch_bounds__(256) void k_ln(const float* __restrict__ x,
                                            const float* __restrict__ lnw,
                                            const float* __restrict__ lnb,
                                            u16* __restrict__ tn_bf) {
    __shared__ float tile[Cn][65];
    __shared__ float red[2][4][64];
    __shared__ float mean_s[64], rstd_s[64];
    int b = blockIdx.x >> 6;
    int l0 = (blockIdx.x & 63) << 6;
    int tid = threadIdx.x;
    for (int idx = tid; idx < Cn * 64; idx += 256) {
        int c = idx >> 6, ll = idx & 63;
        tile[c][ll] = x[((size_t)(b * Cn + c) << 12) + l0 + ll];
    }
    __syncthreads();
    int ll = tid & 63, grp = tid >> 6;
    float s = 0.f, s2 = 0.f;
    for (int c = grp * 48; c < grp * 48 + 48; ++c) {
        float v = tile[c][ll];
        s += v; s2 += v * v;
    }
    red[0][grp][ll] = s; red[1][grp][ll] = s2;
    __syncthreads();
    if (tid < 64) {
        float m = red[0][0][tid] + red[0][1][tid] + red[0][2][tid] + red[0][3][tid];
        float q = red[1][0][tid] + red[1][1][tid] + red[1][2][tid] + red[1][3][tid];
        m *= (1.f / Cn);
        float var = q * (1.f / Cn) - m * m;
        mean_s[tid] = m;
        rstd_s[tid] = rsqrtf(var + EPSf);
    }
    __syncthreads();
    for (int idx = tid; idx < 64 * Cn; idx += 256) {
        int t = idx / Cn, c = idx - t * Cn;
        float v = (tile[c][t] - mean_s[t]) * rstd_s[t] * lnw[c] + lnb[c];
        tn_bf[(size_t)(b * Ln + l0 + t) * Cn + c] = f2bf(v);
    }
}

// ---------------------------------------------------------------- K2: generic bf16 MFMA GEMM
// A (M,K) bf16 rm; W (N,K) fp32 rm -> bf16 staged; out fp32 or bf16 (M,LDO).
template <int BM, int BN, int K, int BK, int NR, int LDO, bool BOUT>
__global__ __launch_bounds__(256) void k_bgemm(const u16* __restrict__ A,
                                               const float* __restrict__ W,
                                               void* __restrict__ outv) {
    constexpr int PK = BK + 8;
    constexpr int MF = BM / 64;
    constexpr int NF = BN / 16;
    constexpr int NCH = BK / 8;
    constexpr int NQ = BK / 4;
    __shared__ __align__(16) u16 As[BM * PK];
    __shared__ __align__(16) u16 Ws_[BN * PK];
    int m0 = blockIdx.x * BM, n0 = blockIdx.y * BN;
    int tid = threadIdx.x;
    int wid = tid >> 6, lane = tid & 63;
    int lrow = lane & 15, lk8 = (lane >> 4) << 3, rowq = lane >> 4;
    f32x4 acc[MF][NF];
#pragma unroll
    for (int i = 0; i < MF; ++i)
#pragma unroll
        for (int j = 0; j < NF; ++j) acc[i][j] = (f32x4){0.f, 0.f, 0.f, 0.f};
    for (int kt = 0; kt < K / BK; ++kt) {
        int k0 = kt * BK;
        for (int idx = tid; idx < BM * NCH; idx += 256) {
            int r = idx / NCH, c2 = idx - r * NCH;
            *(uint4*)&As[r * PK + c2 * 8] =
                *(const uint4*)&A[(size_t)(m0 + r) * K + k0 + c2 * 8];
        }
        for (int idx = tid; idx < BN * NQ; idx += 256) {
            int r = idx / NQ, q = idx - r * NQ;
            ushort4 o = make_ushort4(0, 0, 0, 0);
            if (NR == BN || r < NR) {
                float4 v = *(const float4*)&W[(size_t)(n0 + r) * K + k0 + q * 4];
                o.x = f2bf(v.x); o.y = f2bf(v.y); o.z = f2bf(v.z); o.w = f2bf(v.w);
            }
            *(ushort4*)&Ws_[r * PK + q * 4] = o;
        }
        __syncthreads();
#pragma unroll
        for (int ks = 0; ks < BK / 32; ++ks) {
            bf16x8 a[MF], bfr[NF];
#pragma unroll
            for (int mf = 0; mf < MF; ++mf)
                a[mf] = *(const bf16x8*)&As[(wid * (BM / 4) + mf * 16 + lrow) * PK + ks * 32 + lk8];
#pragma unroll
            for (int nf = 0; nf < NF; ++nf)
                bfr[nf] = *(const bf16x8*)&Ws_[(nf * 16 + lrow) * PK + ks * 32 + lk8];
#pragma unroll
            for (int mf = 0; mf < MF; ++mf)
#pragma unroll
                for (int nf = 0; nf < NF; ++nf)
                    acc[mf][nf] = __builtin_amdgcn_mfma_f32_16x16x32_bf16(a[mf], bfr[nf],
                                                                          acc[mf][nf], 0, 0, 0);
        }
        __syncthreads();
    }
#pragma unroll
    for (int mf = 0; mf < MF; ++mf)
#pragma unroll
        for (int nf = 0; nf < NF; ++nf) {
            int col = n0 + nf * 16 + lrow;
            if (NR != BN && col >= NR) continue;
            int rbase = m0 + wid * (BM / 4) + mf * 16 + rowq * 4;
#pragma unroll
            for (int r = 0; r < 4; ++r) {
                if (BOUT)
                    ((u16*)outv)[(size_t)(rbase + r) * LDO + col] = f2bf(acc[mf][nf][r]);
                else
                    ((float*)outv)[(size_t)(rbase + r) * LDO + col] = acc[mf][nf][r];
            }
        }
}

// ---------------------------------------------------------------- K3: causal depthwise conv1d + SiLU (bf16 in/out)
__global__ __launch_bounds__(256) void k_conv1d(const u16* __restrict__ xz,
                                                const float* __restrict__ cw,
                                                const float* __restrict__ cb,
                                                u16* __restrict__ xt_bf) {
    int g = blockIdx.x * 256 + threadIdx.x;
    int m = g / 96, dq = g - m * 96;
    int d = dq << 2;
    int l = m & (Ln - 1);
    float w_[4][4];
    *(float4*)&w_[0][0] = *(const float4*)&cw[(d + 0) << 2];
    *(float4*)&w_[1][0] = *(const float4*)&cw[(d + 1) << 2];
    *(float4*)&w_[2][0] = *(const float4*)&cw[(d + 2) << 2];
    *(float4*)&w_[3][0] = *(const float4*)&cw[(d + 3) << 2];
    float4 bv = *(const float4*)&cb[d];
    float o_[4] = {bv.x, bv.y, bv.z, bv.w};
    const u16* base = xz + (size_t)m * E2 + d;
#pragma unroll
    for (int j = 0; j < 4; ++j) {
        if (l >= j) {
            ushort4 in4 = *(const ushort4*)(base - (size_t)j * E2);
            o_[0] += bf2f(in4.x) * w_[0][3 - j];
            o_[1] += bf2f(in4.y) * w_[1][3 - j];
            o_[2] += bf2f(in4.z) * w_[2][3 - j];
            o_[3] += bf2f(in4.w) * w_[3][3 - j];
        }
    }
    ushort4 rb;
    rb.x = f2bf(o_[0] * sigmoidf_(o_[0]));
    rb.y = f2bf(o_[1] * sigmoidf_(o_[1]));
    rb.z = f2bf(o_[2] * sigmoidf_(o_[2]));
    rb.w = f2bf(o_[3] * sigmoidf_(o_[3]));
    *(ushort4*)&xt_bf[(size_t)m * DIn + d] = rb;
}

// ---------------------------------------------------------------- K6a: scan pass 1 (dt_proj fused)
__global__ __launch_bounds__(256) void k_scan1(const u16* __restrict__ xt_bf,
                                               const float* __restrict__ dbl,
                                               const float* __restrict__ dtw,
                                               const float* __restrict__ dtb,
                                               const float* __restrict__ alog,
                                               float* __restrict__ chunkA,
                                               float* __restrict__ chunkH) {
    __shared__ float ds_d[16][17], ds_u[16][17], ds_bt[16][17];
    __shared__ float dts[16][13], dtw_s[16][12], dtb_s[16];
    int dg = blockIdx.x, c = blockIdx.y, b = blockIdx.z;
    int tid = threadIdx.x, ch = tid >> 4, n = tid & 15;
    int d = dg * 16 + ch;
    float Av = -__expf(alog[d * Nst + n]);
    int trow = tid >> 4, dd = tid & 15;
    if (tid < 192) dtw_s[tid / 12][tid % 12] = dtw[(dg * 16 + tid / 12) * RK + tid % 12];
    if (tid >= 192 && tid < 208) dtb_s[tid - 192] = dtb[dg * 16 + tid - 192];
    float h = 0.f, ap = 1.f;
    for (int sub = 0; sub < 4; ++sub) {
        int row = b * Ln + c * 64 + sub * 16 + trow;
        ds_u[trow][dd] = bf2f(xt_bf[(size_t)row * DIn + dg * 16 + dd]);
        ds_bt[trow][dd] = dbl[(size_t)row * 44 + 12 + dd];
        if (dd < 12) dts[trow][dd] = dbl[(size_t)row * 44 + dd];
        __syncthreads();
        float acc = dtb_s[dd];
#pragma unroll
        for (int r = 0; r < RK; ++r) acc = fmaf(dts[trow][r], dtw_s[dd][r], acc);
        ds_d[trow][dd] = softplusf_(acc);
        __syncthreads();
#pragma unroll
        for (int tt = 0; tt < 16; ++tt) {
            float de = ds_d[tt][ch], uu = ds_u[tt][ch], bb = ds_bt[tt][n];
            float a = __expf(de * Av);
            ap *= a;
            h = fmaf(a, h, de * uu * bb);
        }
        __syncthreads();
    }
    size_t base = (size_t)(b * NCn + c) * (DIn * Nst) + dg * 256;
    chunkA[base + tid] = ap;
    chunkH[base + tid] = h;
}

// ---------------------------------------------------------------- K6b: scan pass 1.5 — chunk-start states
__global__ __launch_bounds__(256) void k_scan15(const float* __restrict__ chunkA,
                                                const float* __restrict__ chunkH,
                                                float* __restrict__ hstart) {
    int dg = blockIdx.x, b = blockIdx.y;
    int tid = threadIdx.x;
    size_t off = (size_t)b * NCn * (DIn * Nst) + dg * 256 + tid;
    float h = 0.f;
    for (int c0 = 0; c0 < NCn; c0 += 8) {
        float Ar[8], Hr[8];
#pragma unroll
        for (int j = 0; j < 8; ++j) {
            Ar[j] = chunkA[off + (size_t)(c0 + j) * (DIn * Nst)];
            Hr[j] = chunkH[off + (size_t)(c0 + j) * (DIn * Nst)];
        }
#pragma unroll
        for (int j = 0; j < 8; ++j) {
            hstart[off + (size_t)(c0 + j) * (DIn * Nst)] = h;
            h = fmaf(Ar[j], h, Hr[j]);
        }
    }
}

// ---------------------------------------------------------------- K6c: scan pass 2 (dt_proj + gate fused) -> Agate bf16
__global__ __launch_bounds__(256) void k_scan2(const u16* __restrict__ xt_bf,
                                               const float* __restrict__ dbl,
                                               const float* __restrict__ dtw,
                                               const float* __restrict__ dtb,
                                               const float* __restrict__ alog,
                                               const float* __restrict__ hstart,
                                               const u16* __restrict__ xz,
                                               const float* __restrict__ Dp,
                                               u16* __restrict__ agate) {
    __shared__ float ds_d[16][17], ds_u[16][17], ds_bt[16][17], ds_ct[16][17], ds_z[16][17];
    __shared__ float pbuf[16][16][17];
    __shared__ float dts[16][13], dtw_s[16][12], dtb_s[16], Dv_s[16];
    int dg = blockIdx.x, c = blockIdx.y, b = blockIdx.z;
    int tid = threadIdx.x, ch = tid >> 4, n = tid & 15;
    int d = dg * 16 + ch;
    float Av = -__expf(alog[d * Nst + n]);
    int trow = tid >> 4, dd = tid & 15;
    if (tid < 192) dtw_s[tid / 12][tid % 12] = dtw[(dg * 16 + tid / 12) * RK + tid % 12];
    if (tid >= 192 && tid < 208) dtb_s[tid - 192] = dtb[dg * 16 + tid - 192];
    if (tid >= 208 && tid < 224) Dv_s[tid - 208] = Dp[dg * 16 + tid - 208];
    size_t base = (size_t)(b * NCn + c) * (DIn * Nst) + dg * 256;
    float h = hstart[base + tid];
    for (int sub = 0; sub < 4; ++sub) {
        int row = b * Ln + c * 64 + sub * 16 + trow;
        ds_u[trow][dd] = bf2f(xt_bf[(size_t)row * DIn + dg * 16 + dd]);
        ds_bt[trow][dd] = dbl[(size_t)row * 44 + 12 + dd];
        ds_ct[trow][dd] = dbl[(size_t)row * 44 + 28 + dd];
        ds_z[trow][dd] = bf2f(xz[(size_t)row * E2 + DIn + dg * 16 + dd]);
        if (dd < 12) dts[trow][dd] = dbl[(size_t)row * 44 + dd];
        __syncthreads();
        float acc = dtb_s[dd];
#pragma unroll
        for (int r = 0; r < RK; ++r) acc = fmaf(dts[trow][r], dtw_s[dd][r], acc);
        ds_d[trow][dd] = softplusf_(acc);
        __syncthreads();
#pragma unroll
        for (int tt = 0; tt < 16; ++tt) {
            float de = ds_d[tt][ch], uu = ds_u[tt][ch];
            float a = __expf(de * Av);
            h = fmaf(a, h, de * uu * ds_bt[tt][n]);
            pbuf[tt][ch][n] = h * ds_ct[tt][n];
        }
        __syncthreads();
        float s = 0.f;
#pragma unroll
        for (int q = 0; q < 16; ++q) s += pbuf[trow][dd][q];
        float zz = ds_z[trow][dd];
        float ga = (s + ds_u[trow][dd] * Dv_s[dd]) * (zz * sigmoidf_(zz));
        agate[(size_t)row * DIn + dg * 16 + dd] = f2bf(ga);
        __syncthreads();
    }
}

// ---------------------------------------------------------------- K7: out_proj GEMM (bf16 A) + residual -> t2bf
__global__ __launch_bounds__(256) void k_outproj(const u16* __restrict__ agate,
                                                 const float* __restrict__ Wo,
                                                 const float* __restrict__ x,
                                                 u16* __restrict__ t2bf) {
    constexpr int BM = 128, BN = 64, K = DIn, BK = 96;
    constexpr int PK = BK + 8;
    constexpr int NCH = BK / 8;
    constexpr int NQ = BK / 4;
    __shared__ __align__(16) u16 As[BM * PK];
    __shared__ __align__(16) u16 Ws_[BN * PK];
    int m0 = blockIdx.x * BM, n0 = blockIdx.y * BN;
    int tid = threadIdx.x;
    int wid = tid >> 6, lane = tid & 63;
    int lrow = lane & 15, lk8 = (lane >> 4) << 3, rowq = lane >> 4;
    f32x4 acc[2][4];
#pragma unroll
    for (int i = 0; i < 2; ++i)
#pragma unroll
        for (int j = 0; j < 4; ++j) acc[i][j] = (f32x4){0.f, 0.f, 0.f, 0.f};
    for (int kt = 0; kt < K / BK; ++kt) {
        int k0 = kt * BK;
        for (int idx = tid; idx < BM * NCH; idx += 256) {
            int r = idx / NCH, c2 = idx - r * NCH;
            *(uint4*)&As[r * PK + c2 * 8] =
                *(const uint4*)&agate[(size_t)(m0 + r) * K + k0 + c2 * 8];
        }
        for (int idx = tid; idx < BN * NQ; idx += 256) {
            int r = idx / NQ, q = idx - r * NQ;
            float4 v = *(const float4*)&Wo[(size_t)(n0 + r) * K + k0 + q * 4];
            ushort4 o;
            o.x = f2bf(v.x); o.y = f2bf(v.y); o.z = f2bf(v.z); o.w = f2bf(v.w);
            *(ushort4*)&Ws_[r * PK + q * 4] = o;
        }
        __syncthreads();
#pragma unroll
        for (int ks = 0; ks < BK / 32; ++ks) {
            bf16x8 a[2], bfr[4];
#pragma unroll
            for (int mf = 0; mf < 2; ++mf)
                a[mf] = *(const bf16x8*)&As[(wid * 32 + mf * 16 + lrow) * PK + ks * 32 + lk8];
#pragma unroll
            for (int nf = 0; nf < 4; ++nf)
                bfr[nf] = *(const bf16x8*)&Ws_[(nf * 16 + lrow) * PK + ks * 32 + lk8];
#pragma unroll
            for (int mf = 0; mf < 2; ++mf)
#pragma unroll
                for (int nf = 0; nf < 4; ++nf)
                    acc[mf][nf] = __builtin_amdgcn_mfma_f32_16x16x32_bf16(a[mf], bfr[nf],
                                                                          acc[mf][nf], 0, 0, 0);
        }
        __syncthreads();
    }
#pragma unroll
    for (int mf = 0; mf < 2; ++mf)
#pragma unroll
        for (int nf = 0; nf < 4; ++nf) {
            int col = n0 + nf * 16 + lrow;
            int rbase = m0 + wid * 32 + mf * 16 + rowq * 4;
#pragma unroll
            for (int r = 0; r < 4; ++r) {
                int m = rbase + r;
                int b = m >> 12, l = m & 4095;
                float v = acc[mf][nf][r] + x[((size_t)(b * Cn + col) << 12) + l];
                t2bf[(size_t)m * Cn + col] = f2bf(v);
            }
        }
}

// ---------------------------------------------------------------- K8a: rfw fp32 [co][ci][tap] -> bf16 [tap][co][ci]
__global__ __launch_bounds__(256) void k_cvt_rfw(const float* __restrict__ rfw,
                                                 u16* __restrict__ wcv) {
    int g = blockIdx.x * 256 + threadIdx.x;
    if (g >= Cn * Cn * 9) return;
    int tap = g / (Cn * Cn);
    int rem = g - tap * (Cn * Cn);
    int co = rem / Cn, ci = rem - co * Cn;
    wcv[g] = f2bf(rfw[((size_t)co * Cn + ci) * 9 + tap]);
}

// ---------------------------------------------------------------- K8: conv3x3 + BN + ReLU, bf16 MFMA implicit GEMM
__global__ __launch_bounds__(256) void k_conv3(const u16* __restrict__ t2bf,
                                               const u16* __restrict__ wcv,
                                               const float* __restrict__ rfb,
                                               const float* __restrict__ bnw,
                                               const float* __restrict__ bnb,
                                               const float* __restrict__ bnm,
                                               const float* __restrict__ bnv,
                                               float* __restrict__ out) {
    __shared__ __align__(16) u16 in_s[4 * 66 * 40];
    __shared__ __align__(16) u16 w_s[9 * 64 * 40];
    int mt = blockIdx.x;
    int n0 = blockIdx.y << 6;
    int b = mt >> 5;
    int h0 = (mt & 31) << 1;
    int hw0 = h0 << 6;
    int tid = threadIdx.x;
    int wid = tid >> 6, lane = tid & 63;
    int lrow = lane & 15, lk8 = (lane >> 4) << 3, l4 = (lane >> 4) << 2;

    for (int idx = tid; idx < 4 * 40; idx += 256) {
        int rl = idx / 40, k = idx - rl * 40;
        in_s[(rl * 66 + 0) * 40 + k] = 0;
        in_s[(rl * 66 + 65) * 40 + k] = 0;
    }

    int s0 = wid * 32 + lrow;
    int s1 = s0 + 16;
    int abase0 = ((s0 >> 6) * 66 + (s0 & 63)) * 40 + lk8;
    int abase1 = ((s1 >> 6) * 66 + (s1 & 63)) * 40 + lk8;
    int bbase = lrow * 40 + lk8;

    f32x4 acc[2][4];
#pragma unroll
    for (int i = 0; i < 2; ++i)
#pragma unroll
        for (int j = 0; j < 4; ++j) acc[i][j] = (f32x4){0.f, 0.f, 0.f, 0.f};

    int wq = tid >> 2, cq = (tid & 3) << 3;
    for (int ci0 = 0; ci0 < Cn; ci0 += 32) {
        __syncthreads();
#pragma unroll
        for (int rl = 0; rl < 4; ++rl) {
            int gr = h0 - 1 + rl;
            uint4 v = make_uint4(0u, 0u, 0u, 0u);
            if (gr >= 0 && gr < Hn)
                v = *(const uint4*)&t2bf[(size_t)((b << 12) + (gr << 6) + wq) * Cn + ci0 + cq];
            *(uint4*)&in_s[(rl * 66 + wq + 1) * 40 + cq] = v;
        }
#pragma unroll
        for (int tap = 0; tap < 9; ++tap) {
            int co = tid >> 2;
            uint4 v = *(const uint4*)&wcv[((size_t)tap * Cn + n0 + co) * Cn + ci0 + cq];
            *(uint4*)&w_s[(tap * 64 + co) * 40 + cq] = v;
        }
        __syncthreads();
#pragma unroll
        for (int kh = 0; kh < 3; ++kh) {
#pragma unroll
            for (int kw = 0; kw < 3; ++kw) {
                int aoff = (kh * 66 + kw) * 40;
                bf16x8 a0 = *(const bf16x8*)&in_s[abase0 + aoff];
                bf16x8 a1 = *(const bf16x8*)&in_s[abase1 + aoff];
                int boff = (kh * 3 + kw) * 2560;
#pragma unroll
                for (int nf = 0; nf < 4; ++nf) {
                    bf16x8 bb = *(const bf16x8*)&w_s[bbase + nf * 640 + boff];
                    acc[0][nf] = __builtin_amdgcn_mfma_f32_16x16x32_bf16(a0, bb, acc[0][nf], 0, 0, 0);
                    acc[1][nf] = __builtin_amdgcn_mfma_f32_16x16x32_bf16(a1, bb, acc[1][nf], 0, 0, 0);
                }
            }
        }
    }
#pragma unroll
    for (int nf = 0; nf < 4; ++nf) {
        int co = n0 + nf * 16 + lrow;
        float sc = bnw[co] * rsqrtf(bnv[co] + EPSf);
        float sf = (rfb[co] - bnm[co]) * sc + bnb[co];
        size_t obase = ((size_t)(b * Cn + co) << 12) + hw0;
#pragma unroll
        for (int mf = 0; mf < 2; ++mf) {
            int sb = wid * 32 + mf * 16 + l4;
            float4 o;
            o.x = fmaxf(acc[mf][nf][0] * sc + sf, 0.f);
            o.y = fmaxf(acc[mf][nf][1] * sc + sf, 0.f);
            o.z = fmaxf(acc[mf][nf][2] * sc + sf, 0.f);
            o.w = fmaxf(acc[mf][nf][3] * sc + sf, 0.f);
            *(float4*)&out[obase + sb] = o;
        }
    }
}

// ----------------------------------------------------------------
extern "C" void kernel_launch(void* const* d_in, const int* in_sizes, int n_in,
                              void* d_out, int out_size, void* d_ws, size_t ws_size,
                              hipStream_t stream) {
    const float* x    = (const float*)d_in[0];
    const float* lnw  = (const float*)d_in[1];
    const float* lnb  = (const float*)d_in[2];
    const float* inpw = (const float*)d_in[3];
    const float* cw   = (const float*)d_in[4];
    const float* cb   = (const float*)d_in[5];
    const float* xpw  = (const float*)d_in[6];
    const float* dtw  = (const float*)d_in[7];
    const float* dtb  = (const float*)d_in[8];
    const float* alog = (const float*)d_in[9];
    const float* Dp   = (const float*)d_in[10];
    const float* Wo   = (const float*)d_in[11];
    const float* rfw  = (const float*)d_in[12];
    const float* rfb  = (const float*)d_in[13];
    const float* bnw  = (const float*)d_in[14];
    const float* bnb  = (const float*)d_in[15];
    const float* bnm  = (const float*)d_in[16];
    const float* bnv  = (const float*)d_in[17];

    float* ws = (float*)d_ws;
    // region map (floats):
    // [0 .. 1572864)          tn_bf (bf16, ln->inproj) -> t2bf (bf16, outproj->conv3)
    // [1572864 .. 3145728)    hstart (scan15->scan2)
    // [3145728 .. 9437184)    xz (bf16, 16384x768)
    // [9437184 .. 12582912)   xt_bf (bf16, 16384x384)
    // [12582912 .. 13303808)  dbl (fp32, 16384x44)
    // [13303808 .. 16449536)  agate (bf16, 16384x384)
    // [16449536 .. 18022400)  chunkA
    // [18022400 .. 19595264)  chunkH
    // [19595264 .. 19761152)  wcv (bf16, 9*192*192)
    u16* tn_bf    = (u16*)ws;
    u16* t2bf     = (u16*)ws;
    float* hstart = ws + 1572864;
    u16* xz       = (u16*)(ws + 3145728);
    u16* xt_bf    = (u16*)(ws + 9437184);
    float* dbl    = ws + 12582912;
    u16* agate    = (u16*)(ws + 13303808);
    float* chunkA = ws + 16449536;
    float* chunkH = ws + 18022400;
    u16* wcv      = (u16*)(ws + 19595264);

    k_ln<<<Bn * (Ln / 64), 256, 0, stream>>>(x, lnw, lnb, tn_bf);
    k_bgemm<128, 64, Cn, 96, 64, E2, true><<<dim3((Bn * Ln) / 128, E2 / 64), 256, 0, stream>>>(
        tn_bf, inpw, xz);
    k_conv1d<<<(Bn * Ln * (DIn / 4)) / 256, 256, 0, stream>>>(xz, cw, cb, xt_bf);
    k_bgemm<64, 48, DIn, 96, 44, 44, false><<<dim3((Bn * Ln) / 64, 1), 256, 0, stream>>>(
        xt_bf, xpw, dbl);
    k_scan1<<<dim3(DIn / 16, NCn, Bn), 256, 0, stream>>>(xt_bf, dbl, dtw, dtb, alog,
                                                         chunkA, chunkH);
    k_scan15<<<dim3(DIn / 16, Bn), 256, 0, stream>>>(chunkA, chunkH, hstart);
    k_scan2<<<dim3(DIn / 16, NCn, Bn), 256, 0, stream>>>(xt_bf, dbl, dtw, dtb, alog,
                                                         hstart, xz, Dp, agate);
    k_outproj<<<dim3((Bn * Ln) / 128, Cn / 64), 256, 0, stream>>>(agate, Wo, x, t2bf);
    k_cvt_rfw<<<(Cn * Cn * 9 + 255) / 256, 256, 0, stream>>>(rfw, wcv);
    k_conv3<<<dim3(128, Cn / 64), 256, 0, stream>>>(t2bf, wcv, rfb, bnw, bnb, bnm, bnv,
                                                    (float*)d_out);
}